// Round 4
// baseline (121.206 us; speedup 1.0000x reference)
//
#include <hip/hip_runtime.h>
#include <hip/hip_bf16.h>
#include <stdint.h>

// Problem: B=8, S=2048, D=1024, E=8, CAP=512, TOK=16384.
// Outputs (concat f32): hidden[16384*1024], logits[16384*8], expert_index[16384]

typedef __attribute__((ext_vector_type(8))) short short8;   // 8 x bf16 (4 VGPRs)
typedef __attribute__((ext_vector_type(4))) float f32x4;

#define AS1 __attribute__((address_space(1)))
#define AS3 __attribute__((address_space(3)))

static __device__ __forceinline__ uint32_t f2bf(float f) {
  __hip_bfloat16 h = __float2bfloat16(f);
  return (uint32_t)*reinterpret_cast<unsigned short*>(&h);
}

// ---------------- Kernel 1: router (logits f32, softmax top-1) + x -> bf16 ----
__global__ __launch_bounds__(256) void k_router(
    const float* __restrict__ x, const float* __restrict__ gw,
    __hip_bfloat16* __restrict__ xb, float* __restrict__ logits,
    float* __restrict__ tprob, int* __restrict__ texp) {
  __shared__ __align__(16) float gs[8 * 1024];  // gate weights [e][d]
  const int tid = threadIdx.x;
  {
    const float4* g4 = reinterpret_cast<const float4*>(gw);
    float4* s4 = reinterpret_cast<float4*>(gs);
#pragma unroll
    for (int i = 0; i < 8; ++i) s4[tid + 256 * i] = g4[tid + 256 * i];
  }
  __syncthreads();
  const int wave = tid >> 6, lane = tid & 63;
  const int t = blockIdx.x * 4 + wave;  // one wave per token, 4096 blocks
  const float2* x2 = reinterpret_cast<const float2*>(x + (size_t)t * 1024);
  uint32_t* xbu = reinterpret_cast<uint32_t*>(xb + (size_t)t * 1024);
  const float2* g2 = reinterpret_cast<const float2*>(gs);
  float acc[8];
#pragma unroll
  for (int e = 0; e < 8; ++e) acc[e] = 0.f;
#pragma unroll
  for (int kk = 0; kk < 8; ++kk) {
    int p = lane + 64 * kk;  // float2-pair index, lane-stride-1 (conflict-free LDS)
    float2 xv = x2[p];
    xbu[p] = f2bf(xv.x) | (f2bf(xv.y) << 16);
#pragma unroll
    for (int e = 0; e < 8; ++e) {
      float2 g = g2[e * 512 + p];
      acc[e] = fmaf(xv.x, g.x, acc[e]);
      acc[e] = fmaf(xv.y, g.y, acc[e]);
    }
  }
#pragma unroll
  for (int d = 1; d < 64; d <<= 1) {
#pragma unroll
    for (int e = 0; e < 8; ++e) acc[e] += __shfl_xor(acc[e], d, 64);
  }
  if (lane == 0) {
    float m = acc[0];
    int idx = 0;
#pragma unroll
    for (int e = 1; e < 8; ++e)
      if (acc[e] > m) { m = acc[e]; idx = e; }  // strict '>' == argmax-first tiebreak
    float s = 0.f;
#pragma unroll
    for (int e = 0; e < 8; ++e) s += expf(acc[e] - m);
    tprob[t] = 1.0f / s;   // softmax prob of the max logit
    texp[t] = idx;
#pragma unroll
    for (int e = 0; e < 8; ++e) logits[(size_t)t * 8 + e] = acc[e];
  }
}

// ---------------- Kernel 2: expert_w [e][k][n] f32 -> Wt [e][n][k] bf16 -------
__global__ __launch_bounds__(256) void k_wconv(const float* __restrict__ w,
                                               __hip_bfloat16* __restrict__ wt) {
  // grid = 8 * 32 * 32 tiles of 32x32
  const int bx = blockIdx.x;
  const int e = bx >> 10;
  const int rem = bx & 1023;
  const int k0 = (rem >> 5) << 5;
  const int n0 = (rem & 31) << 5;
  __shared__ float tile[32][33];  // +1 pad: no bank conflicts on transpose
  const int tid = threadIdx.x;
  const int c = tid & 31, r0 = tid >> 5;
  const float* ws = w + (size_t)e * 1024 * 1024;
#pragma unroll
  for (int i = 0; i < 4; ++i) {
    int r = r0 + 8 * i;
    tile[r][c] = ws[(size_t)(k0 + r) * 1024 + n0 + c];
  }
  __syncthreads();
  __hip_bfloat16* wd = wt + (size_t)e * 1024 * 1024;
#pragma unroll
  for (int i = 0; i < 4; ++i) {
    int r = r0 + 8 * i;  // n within tile
    wd[(size_t)(n0 + r) * 1024 + k0 + c] = __float2bfloat16(tile[c][r]);
  }
}

// ---------------- Kernel 3: per-batch capacity scan (cumsum of onehot) --------
__global__ __launch_bounds__(256) void k_scan(
    const int* __restrict__ texp, int* __restrict__ slots, int* __restrict__ neb,
    int* __restrict__ keep, float* __restrict__ idx_out) {
  const int b = blockIdx.x;  // grid = 8
  const int tid = threadIdx.x;
  __shared__ int te_s[2048];
#pragma unroll
  for (int i = 0; i < 8; ++i) te_s[tid + 256 * i] = texp[b * 2048 + tid + 256 * i];
  __syncthreads();

  int myte[8], cnt[8];
#pragma unroll
  for (int e = 0; e < 8; ++e) cnt[e] = 0;
#pragma unroll
  for (int j = 0; j < 8; ++j) {  // thread owns 8 consecutive tokens
    int v = te_s[tid * 8 + j];
    myte[j] = v;
#pragma unroll
    for (int e = 0; e < 8; ++e) cnt[e] += (v == e);
  }
  // pack 8 counters into 4 u32 (16-bit fields; totals <= 2048 < 65536)
  unsigned u0 = (unsigned)cnt[0] | ((unsigned)cnt[1] << 16);
  unsigned u1 = (unsigned)cnt[2] | ((unsigned)cnt[3] << 16);
  unsigned u2 = (unsigned)cnt[4] | ((unsigned)cnt[5] << 16);
  unsigned u3 = (unsigned)cnt[6] | ((unsigned)cnt[7] << 16);
  const int lane = tid & 63, wave = tid >> 6;
#pragma unroll
  for (int d = 1; d < 64; d <<= 1) {  // inclusive scan within wave
    unsigned v0 = __shfl_up(u0, d, 64);
    unsigned v1 = __shfl_up(u1, d, 64);
    unsigned v2 = __shfl_up(u2, d, 64);
    unsigned v3 = __shfl_up(u3, d, 64);
    if (lane >= d) { u0 += v0; u1 += v1; u2 += v2; u3 += v3; }
  }
  __shared__ unsigned wtot[4][4];
  if (lane == 63) { wtot[wave][0] = u0; wtot[wave][1] = u1; wtot[wave][2] = u2; wtot[wave][3] = u3; }
  __syncthreads();
  unsigned a0 = 0, a1 = 0, a2 = 0, a3 = 0, s0 = 0, s1 = 0, s2 = 0, s3 = 0;
#pragma unroll
  for (int w = 0; w < 4; ++w) {
    unsigned q0 = wtot[w][0], q1 = wtot[w][1], q2 = wtot[w][2], q3 = wtot[w][3];
    if (w < wave) { a0 += q0; a1 += q1; a2 += q2; a3 += q3; }
    s0 += q0; s1 += q1; s2 += q2; s3 += q3;
  }
  u0 += a0; u1 += a1; u2 += a2; u3 += a3;  // inclusive over whole block
  int base[8];
  base[0] = (int)(u0 & 0xFFFF) - cnt[0]; base[1] = (int)(u0 >> 16) - cnt[1];
  base[2] = (int)(u1 & 0xFFFF) - cnt[2]; base[3] = (int)(u1 >> 16) - cnt[3];
  base[4] = (int)(u2 & 0xFFFF) - cnt[4]; base[5] = (int)(u2 >> 16) - cnt[5];
  base[6] = (int)(u3 & 0xFFFF) - cnt[6]; base[7] = (int)(u3 >> 16) - cnt[7];
  if (tid == 0) {
    int tt[8] = {(int)(s0 & 0xFFFF), (int)(s0 >> 16), (int)(s1 & 0xFFFF), (int)(s1 >> 16),
                 (int)(s2 & 0xFFFF), (int)(s2 >> 16), (int)(s3 & 0xFFFF), (int)(s3 >> 16)};
#pragma unroll
    for (int e = 0; e < 8; ++e) neb[e * 8 + b] = tt[e] < 512 ? tt[e] : 512;
  }
#pragma unroll
  for (int j = 0; j < 8; ++j) {
    int v = myte[j];
    int rank = 0;
#pragma unroll
    for (int e = 0; e < 8; ++e)
      if (v == e) { base[e] += 1; rank = base[e]; }  // 1-based inclusive rank
    int tok = b * 2048 + tid * 8 + j;
    int kp = rank <= 512;
    keep[tok] = kp;
    idx_out[tok] = kp ? (float)v : 0.0f;  // argmax(all-zero mask)=0 for dropped
    if (kp) slots[v * 4096 + b * 512 + rank - 1] = tok;  // deterministic, no atomics
  }
}

// ---------------- Kernel 3b: compact per-(e,b) segments -> per-e lists --------
__global__ __launch_bounds__(256) void k_compact(
    const int* __restrict__ neb, const int* __restrict__ slots,
    int* __restrict__ comp, int* __restrict__ tot) {
  const int e = blockIdx.x;  // grid = 8
  const int tid = threadIdx.x;
  __shared__ int ofs[8];
  if (tid == 0) {
    int s = 0;
#pragma unroll
    for (int b = 0; b < 8; ++b) { ofs[b] = s; s += neb[e * 8 + b]; }
    tot[e] = s;
  }
  __syncthreads();
#pragma unroll
  for (int b = 0; b < 8; ++b) {
    int c = neb[e * 8 + b];
    int o = ofs[b];
    for (int i = tid; i < c; i += 256)
      comp[e * 4096 + o + i] = slots[e * 4096 + b * 512 + i];
  }
}

// ---------------- Kernel 4: gathered expert GEMM, 256x256xBK64, 8 waves ------
// One 256x256 output tile per block -> ~256 blocks total = 1 block/CU, one
// round, no tail. dbuf-2 LDS (128 KB dynamic), counted vmcnt(8) pipeline with
// R3's proven skeleton: [wait vmcnt -> barrier -> compute(lgkm0+sched_barrier)
// -> barrier -> stage(t+2 into just-released buffer)].
// Swizzle: 16B-chunk slot' = slot ^ (row&7) involution on pre-swizzled GLOBAL
// source + ds_read side (rule 21); linear LDS dest for global_load_lds.
__global__ __launch_bounds__(512, 2) void k_gemm(
    const __hip_bfloat16* __restrict__ xb, const __hip_bfloat16* __restrict__ wt,
    const int* __restrict__ comp, const int* __restrict__ tot,
    const float* __restrict__ tprob, float* __restrict__ out) {
  int pf[9];
  pf[0] = 0;
#pragma unroll
  for (int e = 0; e < 8; ++e) pf[e + 1] = pf[e] + ((tot[e] + 255) >> 8) * 4;
  const int T = pf[8];  // <= 512
  const int bid = blockIdx.x;
  if (bid >= T) return;
  // bijective XCD-chunked swizzle (m204)
  const int q8 = T >> 3, r8 = T & 7, xcd = bid & 7, pos = bid >> 3;
  const int tile = (xcd < r8 ? xcd * (q8 + 1) : r8 * (q8 + 1) + (xcd - r8) * q8) + pos;
  int e = 0;
#pragma unroll
  for (int k = 0; k < 8; ++k)
    if (tile >= pf[k + 1]) e = k + 1;
  const int local = tile - pf[e];
  const int rt = local >> 2;  // 256-row tile index
  const int ct = local & 3;   // 256-col tile index
  int nvalid = tot[e] - rt * 256;
  if (nvalid > 256) nvalid = 256;

  extern __shared__ __align__(16) char dynls[];  // 2 bufs x (A 32KB + B 32KB)
  __shared__ int rid_s[256];
  __shared__ float tp_s[256];

  const int tid = threadIdx.x;  // 0..511
  const int* seg = comp + e * 4096 + rt * 256;
  if (tid < 256) {
    int rid = seg[(tid < nvalid) ? tid : 0];  // dummy rows -> row 0 (store-masked)
    rid_s[tid] = rid;
    tp_s[tid] = tprob[rid];
  }
  __syncthreads();

  const int wave = tid >> 6, lane = tid & 63;
  const int wm = wave >> 2, wn = wave & 3;  // 2x4 wave grid; 128x64 out per wave

  // Staging: per K-tile, A = 256 rows x 8 chunks(16B) = 2048 chunks; 512 thr ->
  // 4 chunks/thread; same for B. Linear LDS dest, swizzled global source:
  // kl = slot ^ (row&7).  row = cid>>3, slot = cid&7, cid = p*512+tid.
  const __hip_bfloat16* wte = wt + (size_t)e * 1024 * 1024;
  const __hip_bfloat16* pa[4];
  const __hip_bfloat16* pb[4];
#pragma unroll
  for (int p = 0; p < 4; ++p) {
    int cid = p * 512 + tid;
    int row = cid >> 3, slot = cid & 7;
    int kl = slot ^ (row & 7);
    pa[p] = xb + (size_t)rid_s[row] * 1024 + kl * 8;
    pb[p] = wte + (size_t)(ct * 256 + row) * 1024 + kl * 8;
  }

#define STAGE(kti, bufi)                                                            \
  do {                                                                              \
    char* db_ = dynls + (bufi) * 65536;                                             \
    _Pragma("unroll") for (int p = 0; p < 4; ++p) {                                 \
      __builtin_amdgcn_global_load_lds((const AS1 uint32_t*)(pa[p] + (kti) * 64),   \
                                       (AS3 uint32_t*)(db_ + (p * 512 + tid) * 16), 16, 0, 0); \
      __builtin_amdgcn_global_load_lds((const AS1 uint32_t*)(pb[p] + (kti) * 64),   \
                                       (AS3 uint32_t*)(db_ + 32768 + (p * 512 + tid) * 16), 16, 0, 0); \
    }                                                                               \
  } while (0)

  f32x4 acc[8][4];
#pragma unroll
  for (int i = 0; i < 8; ++i)
#pragma unroll
    for (int j = 0; j < 4; ++j) acc[i][j] = 0.f;

  const int frow = lane & 15;
  const int qq = lane >> 4;
  const int sw = frow & 7;
  const int abase = (wm * 128 + frow) * 64;  // element offset in A tile [256][64]
  const int bbase = (wn * 64 + frow) * 64;   // element offset in B tile [256][64]
  const int sl0 = (qq) ^ sw;                 // phys 16B slot, k-substep 0
  const int sl1 = (4 + qq) ^ sw;             // phys 16B slot, k-substep 1

#define COMPUTE(bufi)                                                               \
  do {                                                                              \
    const __hip_bfloat16* As = (const __hip_bfloat16*)(dynls + (bufi) * 65536);     \
    const __hip_bfloat16* Bs = As + 16384;                                          \
    _Pragma("unroll") for (int ks = 0; ks < 2; ++ks) {                              \
      const int slk = ks ? sl1 : sl0;                                               \
      short8 a[8], b[4];                                                            \
      _Pragma("unroll") for (int mi = 0; mi < 8; ++mi)                              \
          a[mi] = *reinterpret_cast<const short8*>(&As[abase + mi * 1024 + slk * 8]); \
      _Pragma("unroll") for (int ni = 0; ni < 4; ++ni)                              \
          b[ni] = *reinterpret_cast<const short8*>(&Bs[bbase + ni * 1024 + slk * 8]); \
      asm volatile("s_waitcnt lgkmcnt(0)" ::: "memory");                            \
      __builtin_amdgcn_sched_barrier(0);                                            \
      __builtin_amdgcn_s_setprio(1);                                                \
      _Pragma("unroll") for (int mi = 0; mi < 8; ++mi)                              \
          _Pragma("unroll") for (int ni = 0; ni < 4; ++ni)                          \
              acc[mi][ni] = __builtin_amdgcn_mfma_f32_16x16x32_bf16(a[mi], b[ni], acc[mi][ni], 0, 0, 0); \
      __builtin_amdgcn_s_setprio(0);                                                \
    }                                                                               \
  } while (0)

  STAGE(0, 0);
  STAGE(1, 1);
  for (int t = 0; t < 16; ++t) {
    // K-tile t resident once our own 8 loads for it land; barrier makes it
    // globally resident (every wave waited its own before crossing).
    if (t < 15) {
      asm volatile("s_waitcnt vmcnt(8)" ::: "memory");
    } else {
      asm volatile("s_waitcnt vmcnt(0)" ::: "memory");
    }
    __builtin_amdgcn_s_barrier();
    __builtin_amdgcn_sched_barrier(0);
    COMPUTE(t & 1);
    __builtin_amdgcn_s_barrier();  // all waves done reading buf[t&1]
    __builtin_amdgcn_sched_barrier(0);
    if (t + 2 < 16) STAGE(t + 2, t & 1);
  }
#undef COMPUTE
#undef STAGE

  // C/D layout: col = lane&15, row = (lane>>4)*4 + j   [m89-verified]
  const int colb = ct * 256 + wn * 64 + frow;
  const int rowb = wm * 128 + qq * 4;
#pragma unroll
  for (int mi = 0; mi < 8; ++mi) {
#pragma unroll
    for (int j = 0; j < 4; ++j) {
      int r = rowb + mi * 16 + j;
      if (r < nvalid) {
        size_t ro = (size_t)rid_s[r] * 1024;
        float sc = tp_s[r];
#pragma unroll
        for (int ni = 0; ni < 4; ++ni)
          out[ro + colb + ni * 16] = sc * acc[mi][ni][j];
      }
    }
  }
}

// ---------------- Kernel 5: identity pass-through for dropped tokens ----------
__global__ __launch_bounds__(256) void k_identity(
    const float* __restrict__ x, const float* __restrict__ tprob,
    const int* __restrict__ keep, float* __restrict__ out) {
  const int t0 = blockIdx.x * 8;  // grid = 2048
  const int tid = threadIdx.x;
#pragma unroll
  for (int j = 0; j < 8; ++j) {
    int t = t0 + j;
    if (!keep[t]) {
      float s = tprob[t];
      const float4* xi = reinterpret_cast<const float4*>(x + (size_t)t * 1024);
      float4* o = reinterpret_cast<float4*>(out + (size_t)t * 1024);
      float4 v = xi[tid];
      o[tid] = make_float4(s * v.x, s * v.y, s * v.z, s * v.w);
    }
  }
}

extern "C" void kernel_launch(void* const* d_in, const int* in_sizes, int n_in,
                              void* d_out, int out_size, void* d_ws, size_t ws_size,
                              hipStream_t stream) {
  const float* x = (const float*)d_in[0];    // [8,2048,1024]
  const float* gw = (const float*)d_in[1];   // [8,1024]
  const float* w = (const float*)d_in[2];    // [8,1024,1024]
  float* out = (float*)d_out;
  float* logits = out + (size_t)16384 * 1024;
  float* idx_out = logits + (size_t)16384 * 8;

  // workspace layout (~50.8 MB total)
  char* ws = (char*)d_ws;
  __hip_bfloat16* xb = (__hip_bfloat16*)(ws);              // 33554432 B
  __hip_bfloat16* wt = (__hip_bfloat16*)(ws + 33554432);   // 16777216 B
  float* tprob = (float*)(ws + 50331648);                  // 65536 B
  int* texp   = (int*)(ws + 50397184);                     // 65536 B
  int* keep   = (int*)(ws + 50462720);                     // 65536 B
  int* slots  = (int*)(ws + 50528256);                     // 131072 B
  int* neb    = (int*)(ws + 50659328);                     // 256 B
  int* comp   = (int*)(ws + 50659584);                     // 131072 B
  int* tot    = (int*)(ws + 50790656);                     // 32 B

  hipLaunchKernelGGL(k_router,   dim3(4096), dim3(256), 0, stream, x, gw, xb, logits, tprob, texp);
  hipLaunchKernelGGL(k_wconv,    dim3(8192), dim3(256), 0, stream, w, wt);
  hipLaunchKernelGGL(k_scan,     dim3(8),    dim3(256), 0, stream, texp, slots, neb, keep, idx_out);
  hipLaunchKernelGGL(k_compact,  dim3(8),    dim3(256), 0, stream, neb, slots, comp, tot);
  hipLaunchKernelGGL(k_gemm,     dim3(512),  dim3(512), 131072, stream, xb, wt, comp, tot, tprob, out);
  hipLaunchKernelGGL(k_identity, dim3(2048), dim3(256), 0, stream, x, tprob, keep, out);
}

// Round 5
// 117.247 us; speedup vs baseline: 1.0338x; 1.0338x over previous
//
#include <hip/hip_runtime.h>
#include <hip/hip_bf16.h>
#include <stdint.h>

// Problem: B=8, S=2048, D=1024, E=8, CAP=512, TOK=16384.
// Outputs (concat f32): hidden[16384*1024], logits[16384*8], expert_index[16384]

typedef __attribute__((ext_vector_type(8))) short short8;   // 8 x bf16 (4 VGPRs)
typedef __attribute__((ext_vector_type(4))) float f32x4;

#define AS1 __attribute__((address_space(1)))
#define AS3 __attribute__((address_space(3)))

static __device__ __forceinline__ uint32_t f2bf(float f) {
  __hip_bfloat16 h = __float2bfloat16(f);
  return (uint32_t)*reinterpret_cast<unsigned short*>(&h);
}

// ---------------- Kernel 1: router (logits f32, softmax top-1) + x -> bf16 ----
__global__ __launch_bounds__(256) void k_router(
    const float* __restrict__ x, const float* __restrict__ gw,
    __hip_bfloat16* __restrict__ xb, float* __restrict__ logits,
    float* __restrict__ tprob, int* __restrict__ texp) {
  __shared__ __align__(16) float gs[8 * 1024];  // gate weights [e][d]
  const int tid = threadIdx.x;
  {
    const float4* g4 = reinterpret_cast<const float4*>(gw);
    float4* s4 = reinterpret_cast<float4*>(gs);
#pragma unroll
    for (int i = 0; i < 8; ++i) s4[tid + 256 * i] = g4[tid + 256 * i];
  }
  __syncthreads();
  const int wave = tid >> 6, lane = tid & 63;
  const int t = blockIdx.x * 4 + wave;  // one wave per token, 4096 blocks
  const float2* x2 = reinterpret_cast<const float2*>(x + (size_t)t * 1024);
  uint32_t* xbu = reinterpret_cast<uint32_t*>(xb + (size_t)t * 1024);
  const float2* g2 = reinterpret_cast<const float2*>(gs);
  float acc[8];
#pragma unroll
  for (int e = 0; e < 8; ++e) acc[e] = 0.f;
#pragma unroll
  for (int kk = 0; kk < 8; ++kk) {
    int p = lane + 64 * kk;  // float2-pair index, lane-stride-1 (conflict-free LDS)
    float2 xv = x2[p];
    xbu[p] = f2bf(xv.x) | (f2bf(xv.y) << 16);
#pragma unroll
    for (int e = 0; e < 8; ++e) {
      float2 g = g2[e * 512 + p];
      acc[e] = fmaf(xv.x, g.x, acc[e]);
      acc[e] = fmaf(xv.y, g.y, acc[e]);
    }
  }
#pragma unroll
  for (int d = 1; d < 64; d <<= 1) {
#pragma unroll
    for (int e = 0; e < 8; ++e) acc[e] += __shfl_xor(acc[e], d, 64);
  }
  if (lane == 0) {
    float m = acc[0];
    int idx = 0;
#pragma unroll
    for (int e = 1; e < 8; ++e)
      if (acc[e] > m) { m = acc[e]; idx = e; }  // strict '>' == argmax-first tiebreak
    float s = 0.f;
#pragma unroll
    for (int e = 0; e < 8; ++e) s += expf(acc[e] - m);
    tprob[t] = 1.0f / s;   // softmax prob of the max logit
    texp[t] = idx;
#pragma unroll
    for (int e = 0; e < 8; ++e) logits[(size_t)t * 8 + e] = acc[e];
  }
}

// ---------------- Kernel 2: expert_w [e][k][n] f32 -> Wt [e][n][k] bf16 -------
__global__ __launch_bounds__(256) void k_wconv(const float* __restrict__ w,
                                               __hip_bfloat16* __restrict__ wt) {
  // grid = 8 * 32 * 32 tiles of 32x32
  const int bx = blockIdx.x;
  const int e = bx >> 10;
  const int rem = bx & 1023;
  const int k0 = (rem >> 5) << 5;
  const int n0 = (rem & 31) << 5;
  __shared__ float tile[32][33];  // +1 pad: no bank conflicts on transpose
  const int tid = threadIdx.x;
  const int c = tid & 31, r0 = tid >> 5;
  const float* ws = w + (size_t)e * 1024 * 1024;
#pragma unroll
  for (int i = 0; i < 4; ++i) {
    int r = r0 + 8 * i;
    tile[r][c] = ws[(size_t)(k0 + r) * 1024 + n0 + c];
  }
  __syncthreads();
  __hip_bfloat16* wd = wt + (size_t)e * 1024 * 1024;
#pragma unroll
  for (int i = 0; i < 4; ++i) {
    int r = r0 + 8 * i;  // n within tile
    wd[(size_t)(n0 + r) * 1024 + k0 + c] = __float2bfloat16(tile[c][r]);
  }
}

// ---------------- Kernel 3: per-batch capacity scan (cumsum of onehot) --------
__global__ __launch_bounds__(256) void k_scan(
    const int* __restrict__ texp, int* __restrict__ slots, int* __restrict__ neb,
    int* __restrict__ keep, float* __restrict__ idx_out) {
  const int b = blockIdx.x;  // grid = 8
  const int tid = threadIdx.x;
  __shared__ int te_s[2048];
#pragma unroll
  for (int i = 0; i < 8; ++i) te_s[tid + 256 * i] = texp[b * 2048 + tid + 256 * i];
  __syncthreads();

  int myte[8], cnt[8];
#pragma unroll
  for (int e = 0; e < 8; ++e) cnt[e] = 0;
#pragma unroll
  for (int j = 0; j < 8; ++j) {  // thread owns 8 consecutive tokens
    int v = te_s[tid * 8 + j];
    myte[j] = v;
#pragma unroll
    for (int e = 0; e < 8; ++e) cnt[e] += (v == e);
  }
  // pack 8 counters into 4 u32 (16-bit fields; totals <= 2048 < 65536)
  unsigned u0 = (unsigned)cnt[0] | ((unsigned)cnt[1] << 16);
  unsigned u1 = (unsigned)cnt[2] | ((unsigned)cnt[3] << 16);
  unsigned u2 = (unsigned)cnt[4] | ((unsigned)cnt[5] << 16);
  unsigned u3 = (unsigned)cnt[6] | ((unsigned)cnt[7] << 16);
  const int lane = tid & 63, wave = tid >> 6;
#pragma unroll
  for (int d = 1; d < 64; d <<= 1) {  // inclusive scan within wave
    unsigned v0 = __shfl_up(u0, d, 64);
    unsigned v1 = __shfl_up(u1, d, 64);
    unsigned v2 = __shfl_up(u2, d, 64);
    unsigned v3 = __shfl_up(u3, d, 64);
    if (lane >= d) { u0 += v0; u1 += v1; u2 += v2; u3 += v3; }
  }
  __shared__ unsigned wtot[4][4];
  if (lane == 63) { wtot[wave][0] = u0; wtot[wave][1] = u1; wtot[wave][2] = u2; wtot[wave][3] = u3; }
  __syncthreads();
  unsigned a0 = 0, a1 = 0, a2 = 0, a3 = 0, s0 = 0, s1 = 0, s2 = 0, s3 = 0;
#pragma unroll
  for (int w = 0; w < 4; ++w) {
    unsigned q0 = wtot[w][0], q1 = wtot[w][1], q2 = wtot[w][2], q3 = wtot[w][3];
    if (w < wave) { a0 += q0; a1 += q1; a2 += q2; a3 += q3; }
    s0 += q0; s1 += q1; s2 += q2; s3 += q3;
  }
  u0 += a0; u1 += a1; u2 += a2; u3 += a3;  // inclusive over whole block
  int base[8];
  base[0] = (int)(u0 & 0xFFFF) - cnt[0]; base[1] = (int)(u0 >> 16) - cnt[1];
  base[2] = (int)(u1 & 0xFFFF) - cnt[2]; base[3] = (int)(u1 >> 16) - cnt[3];
  base[4] = (int)(u2 & 0xFFFF) - cnt[4]; base[5] = (int)(u2 >> 16) - cnt[5];
  base[6] = (int)(u3 & 0xFFFF) - cnt[6]; base[7] = (int)(u3 >> 16) - cnt[7];
  if (tid == 0) {
    int tt[8] = {(int)(s0 & 0xFFFF), (int)(s0 >> 16), (int)(s1 & 0xFFFF), (int)(s1 >> 16),
                 (int)(s2 & 0xFFFF), (int)(s2 >> 16), (int)(s3 & 0xFFFF), (int)(s3 >> 16)};
#pragma unroll
    for (int e = 0; e < 8; ++e) neb[e * 8 + b] = tt[e] < 512 ? tt[e] : 512;
  }
#pragma unroll
  for (int j = 0; j < 8; ++j) {
    int v = myte[j];
    int rank = 0;
#pragma unroll
    for (int e = 0; e < 8; ++e)
      if (v == e) { base[e] += 1; rank = base[e]; }  // 1-based inclusive rank
    int tok = b * 2048 + tid * 8 + j;
    int kp = rank <= 512;
    keep[tok] = kp;
    idx_out[tok] = kp ? (float)v : 0.0f;  // argmax(all-zero mask)=0 for dropped
    if (kp) slots[v * 4096 + b * 512 + rank - 1] = tok;  // deterministic, no atomics
  }
}

// ---------------- Kernel 3b: compact per-(e,b) segments -> per-e lists --------
__global__ __launch_bounds__(256) void k_compact(
    const int* __restrict__ neb, const int* __restrict__ slots,
    int* __restrict__ comp, int* __restrict__ tot) {
  const int e = blockIdx.x;  // grid = 8
  const int tid = threadIdx.x;
  __shared__ int ofs[8];
  if (tid == 0) {
    int s = 0;
#pragma unroll
    for (int b = 0; b < 8; ++b) { ofs[b] = s; s += neb[e * 8 + b]; }
    tot[e] = s;
  }
  __syncthreads();
#pragma unroll
  for (int b = 0; b < 8; ++b) {
    int c = neb[e * 8 + b];
    int o = ofs[b];
    for (int i = tid; i < c; i += 256)
      comp[e * 4096 + o + i] = slots[e * 4096 + b * 512 + i];
  }
}

// ---------------- Kernel 4: gathered expert GEMM, 256x256xBK64, 8-PHASE ------
// 8 waves (2Mx4N), per-wave 128x64 out (acc[8][4]). LDS: 2 bufs x (A 32K+B 32K);
// each buf holds one K-tile (BK=64) split into K-halves kh0/kh1 of 16KB each.
// Per K-tile group: 4 phases (ks-major): {ds_read 4-8 b128; stage 1 half-tile
// (2 gload_lds); barrier; lgkm0+sched_barrier; setprio(1); 16 MFMA; setprio(0);
// [counted vmcnt(8) at ph1/ph3 only]; barrier}.
// Stage rotation at group u: ph0 A(u+1).kh1, ph1 B(u+1).kh1, ph2 A(u+2).kh0,
// ph3 B(u+2).kh0. Event-order check: every half is >=8 loads old at its
// guaranteeing vmcnt(8); every LDS overwrite is issued >=1 barrier after the
// last reader's lgkm0 (WAR-safe). vmcnt never drains to 0 until u=15.
// Swizzle (rule 21): 16B slot' = slot ^ ((row>>1)&3) on pre-swizzled global
// source; read side uses slot = qq ^ ((frow>>1)&3) -> all 8 bank-quads covered.
__global__ __launch_bounds__(512, 2) void k_gemm(
    const __hip_bfloat16* __restrict__ xb, const __hip_bfloat16* __restrict__ wt,
    const int* __restrict__ comp, const int* __restrict__ tot,
    const float* __restrict__ tprob, float* __restrict__ out) {
  int pf[9];
  pf[0] = 0;
#pragma unroll
  for (int e = 0; e < 8; ++e) pf[e + 1] = pf[e] + ((tot[e] + 255) >> 8) * 4;
  const int T = pf[8];  // <= 288
  const int bid = blockIdx.x;
  if (bid >= T) return;
  // bijective XCD-chunked swizzle (m204)
  const int q8 = T >> 3, r8 = T & 7, xcd = bid & 7, pos = bid >> 3;
  const int tile = (xcd < r8 ? xcd * (q8 + 1) : r8 * (q8 + 1) + (xcd - r8) * q8) + pos;
  int e = 0;
#pragma unroll
  for (int k = 0; k < 8; ++k)
    if (tile >= pf[k + 1]) e = k + 1;
  const int local = tile - pf[e];
  const int rt = local >> 2;  // 256-row tile index
  const int ct = local & 3;   // 256-col tile index
  int nvalid = tot[e] - rt * 256;
  if (nvalid > 256) nvalid = 256;

  extern __shared__ __align__(16) char dynls[];  // 131072 B: buf*65536 + {A:0,B:32768} + kh*16384
  __shared__ int rid_s[256];
  __shared__ float tp_s[256];

  const int tid = threadIdx.x;  // 0..511
  const int* seg = comp + e * 4096 + rt * 256;
  if (tid < 256) {
    int rid = seg[(tid < nvalid) ? tid : 0];  // dummy rows -> row 0 (store-masked)
    rid_s[tid] = rid;
    tp_s[tid] = tprob[rid];
  }
  __syncthreads();

  const int wave = tid >> 6, lane = tid & 63;
  const int wm = wave >> 2, wn = wave & 3;  // 2x4 wave grid; 128x64 out per wave
  const int frow = lane & 15, qq = lane >> 4;
  const int sw = (frow >> 1) & 3;

  // stage pointers: chunk cid = p*512+tid -> row = cid>>2, slot = cid&3;
  // source k elem = (slot ^ ((row>>1)&3))*8, advanced +32 elems per event.
  const __hip_bfloat16* wte = wt + ((size_t)e << 20);
  const __hip_bfloat16 *pA0, *pA1, *pB0, *pB1;
  {
    int r0 = tid >> 2, r1 = 128 + (tid >> 2), slot = tid & 3;
    int kl0 = (slot ^ ((r0 >> 1) & 3)) * 8;
    int kl1 = (slot ^ ((r1 >> 1) & 3)) * 8;
    pA0 = xb + (size_t)rid_s[r0] * 1024 + kl0;
    pA1 = xb + (size_t)rid_s[r1] * 1024 + kl1;
    pB0 = wte + (size_t)(ct * 256 + r0) * 1024 + kl0;
    pB1 = wte + (size_t)(ct * 256 + r1) * 1024 + kl1;
  }

#define STAGE_A(bufi, kh)                                                        \
  do {                                                                           \
    char* d_ = dynls + (bufi) * 65536 + (kh) * 16384;                            \
    __builtin_amdgcn_global_load_lds((const AS1 uint32_t*)pA0,                   \
                                     (AS3 uint32_t*)(d_ + tid * 16), 16, 0, 0);  \
    __builtin_amdgcn_global_load_lds((const AS1 uint32_t*)pA1,                   \
                                     (AS3 uint32_t*)(d_ + 8192 + tid * 16), 16, 0, 0); \
    pA0 += 32; pA1 += 32;                                                        \
  } while (0)
#define STAGE_B(bufi, kh)                                                        \
  do {                                                                           \
    char* d_ = dynls + (bufi) * 65536 + 32768 + (kh) * 16384;                    \
    __builtin_amdgcn_global_load_lds((const AS1 uint32_t*)pB0,                   \
                                     (AS3 uint32_t*)(d_ + tid * 16), 16, 0, 0);  \
    __builtin_amdgcn_global_load_lds((const AS1 uint32_t*)pB1,                   \
                                     (AS3 uint32_t*)(d_ + 8192 + tid * 16), 16, 0, 0); \
    pB0 += 32; pB1 += 32;                                                        \
  } while (0)

  f32x4 acc[8][4];
#pragma unroll
  for (int i = 0; i < 8; ++i)
#pragma unroll
    for (int j = 0; j < 4; ++j) acc[i][j] = 0.f;

  const int aoffb = (wm * 128 + frow) * 64 + (qq ^ sw) * 16;  // bytes into A kh region
  const int boffb = (wn * 64 + frow) * 64 + (qq ^ sw) * 16;   // bytes into B kh region

  // prologue: K0.kh0, K0.kh1, K1.kh0 (event order defines vmcnt windows)
  STAGE_A(0, 0); STAGE_B(0, 0);
  STAGE_A(0, 1); STAGE_B(0, 1);
  STAGE_A(1, 0); STAGE_B(1, 0);
  asm volatile("s_waitcnt vmcnt(8)" ::: "memory");  // K0.kh0 (A+B) landed
  __builtin_amdgcn_s_barrier();
  __builtin_amdgcn_sched_barrier(0);

#define RA(mi, ks) (*reinterpret_cast<const short8*>(Ab + (ks) * 16384 + aoffb + (mi) * 1024))
#define RB(ni, ks) (*reinterpret_cast<const short8*>(Bb + (ks) * 16384 + boffb + (ni) * 1024))
#define MM(A_, B_, M_, N_) acc[M_][N_] = __builtin_amdgcn_mfma_f32_16x16x32_bf16(A_, B_, acc[M_][N_], 0, 0, 0)
#define MFMA_Q(M0_)                                                              \
  do {                                                                           \
    __builtin_amdgcn_s_setprio(1);                                               \
    MM(a0, b0, M0_ + 0, 0); MM(a0, b1, M0_ + 0, 1); MM(a0, b2, M0_ + 0, 2); MM(a0, b3, M0_ + 0, 3); \
    MM(a1, b0, M0_ + 1, 0); MM(a1, b1, M0_ + 1, 1); MM(a1, b2, M0_ + 1, 2); MM(a1, b3, M0_ + 1, 3); \
    MM(a2, b0, M0_ + 2, 0); MM(a2, b1, M0_ + 2, 1); MM(a2, b2, M0_ + 2, 2); MM(a2, b3, M0_ + 2, 3); \
    MM(a3, b0, M0_ + 3, 0); MM(a3, b1, M0_ + 3, 1); MM(a3, b2, M0_ + 3, 2); MM(a3, b3, M0_ + 3, 3); \
    __builtin_amdgcn_s_setprio(0);                                               \
  } while (0)
#define GATE()                                             \
  do {                                                     \
    __builtin_amdgcn_s_barrier();                          \
    asm volatile("s_waitcnt lgkmcnt(0)" ::: "memory");     \
    __builtin_amdgcn_sched_barrier(0);                     \
  } while (0)

  for (int u = 0; u < 16; ++u) {
    const char* Ab = dynls + (u & 1) * 65536;
    const char* Bb = Ab + 32768;
    short8 a0, a1, a2, a3, b0, b1, b2, b3;

    // ---- phase 0: ks0, mi 0-3 (+b ks0); stage A(u+1).kh1
    a0 = RA(0, 0); a1 = RA(1, 0); a2 = RA(2, 0); a3 = RA(3, 0);
    b0 = RB(0, 0); b1 = RB(1, 0); b2 = RB(2, 0); b3 = RB(3, 0);
    if (u < 15) STAGE_A((u + 1) & 1, 1);
    GATE();
    MFMA_Q(0);
    __builtin_amdgcn_s_barrier();

    // ---- phase 1: ks0, mi 4-7; stage B(u+1).kh1; vmcnt
    a0 = RA(4, 0); a1 = RA(5, 0); a2 = RA(6, 0); a3 = RA(7, 0);
    if (u < 15) STAGE_B((u + 1) & 1, 1);
    GATE();
    MFMA_Q(4);
    if (u < 15) { asm volatile("s_waitcnt vmcnt(8)" ::: "memory"); }
    else        { asm volatile("s_waitcnt vmcnt(0)" ::: "memory"); }
    __builtin_amdgcn_s_barrier();

    // ---- phase 2: ks1, mi 0-3 (+b ks1); stage A(u+2).kh0
    a0 = RA(0, 1); a1 = RA(1, 1); a2 = RA(2, 1); a3 = RA(3, 1);
    b0 = RB(0, 1); b1 = RB(1, 1); b2 = RB(2, 1); b3 = RB(3, 1);
    if (u < 14) STAGE_A(u & 1, 0);
    GATE();
    MFMA_Q(0);
    __builtin_amdgcn_s_barrier();

    // ---- phase 3: ks1, mi 4-7; stage B(u+2).kh0; vmcnt
    a0 = RA(4, 1); a1 = RA(5, 1); a2 = RA(6, 1); a3 = RA(7, 1);
    if (u < 14) STAGE_B(u & 1, 0);
    GATE();
    MFMA_Q(4);
    if (u < 14)      { asm volatile("s_waitcnt vmcnt(8)" ::: "memory"); }
    else if (u == 14){ asm volatile("s_waitcnt vmcnt(4)" ::: "memory"); }
    __builtin_amdgcn_s_barrier();
  }
#undef GATE
#undef MFMA_Q
#undef MM
#undef RB
#undef RA
#undef STAGE_B
#undef STAGE_A

  // C/D layout: col = lane&15, row = (lane>>4)*4 + j   [m89-verified]
  const int colb = ct * 256 + wn * 64 + frow;
  const int rowb = wm * 128 + qq * 4;
#pragma unroll
  for (int mi = 0; mi < 8; ++mi) {
#pragma unroll
    for (int j = 0; j < 4; ++j) {
      int r = rowb + mi * 16 + j;
      if (r < nvalid) {
        size_t ro = (size_t)rid_s[r] * 1024;
        float sc = tp_s[r];
#pragma unroll
        for (int ni = 0; ni < 4; ++ni)
          out[ro + colb + ni * 16] = sc * acc[mi][ni][j];
      }
    }
  }
}

// ---------------- Kernel 5: identity pass-through for dropped tokens ----------
__global__ __launch_bounds__(256) void k_identity(
    const float* __restrict__ x, const float* __restrict__ tprob,
    const int* __restrict__ keep, float* __restrict__ out) {
  const int t0 = blockIdx.x * 8;  // grid = 2048
  const int tid = threadIdx.x;
#pragma unroll
  for (int j = 0; j < 8; ++j) {
    int t = t0 + j;
    if (!keep[t]) {
      float s = tprob[t];
      const float4* xi = reinterpret_cast<const float4*>(x + (size_t)t * 1024);
      float4* o = reinterpret_cast<float4*>(out + (size_t)t * 1024);
      float4 v = xi[tid];
      o[tid] = make_float4(s * v.x, s * v.y, s * v.z, s * v.w);
    }
  }
}

extern "C" void kernel_launch(void* const* d_in, const int* in_sizes, int n_in,
                              void* d_out, int out_size, void* d_ws, size_t ws_size,
                              hipStream_t stream) {
  const float* x = (const float*)d_in[0];    // [8,2048,1024]
  const float* gw = (const float*)d_in[1];   // [8,1024]
  const float* w = (const float*)d_in[2];    // [8,1024,1024]
  float* out = (float*)d_out;
  float* logits = out + (size_t)16384 * 1024;
  float* idx_out = logits + (size_t)16384 * 8;

  // workspace layout (~50.8 MB total)
  char* ws = (char*)d_ws;
  __hip_bfloat16* xb = (__hip_bfloat16*)(ws);              // 33554432 B
  __hip_bfloat16* wt = (__hip_bfloat16*)(ws + 33554432);   // 16777216 B
  float* tprob = (float*)(ws + 50331648);                  // 65536 B
  int* texp   = (int*)(ws + 50397184);                     // 65536 B
  int* keep   = (int*)(ws + 50462720);                     // 65536 B
  int* slots  = (int*)(ws + 50528256);                     // 131072 B
  int* neb    = (int*)(ws + 50659328);                     // 256 B
  int* comp   = (int*)(ws + 50659584);                     // 131072 B
  int* tot    = (int*)(ws + 50790656);                     // 32 B

  hipLaunchKernelGGL(k_router,   dim3(4096), dim3(256), 0, stream, x, gw, xb, logits, tprob, texp);
  hipLaunchKernelGGL(k_wconv,    dim3(8192), dim3(256), 0, stream, w, wt);
  hipLaunchKernelGGL(k_scan,     dim3(8),    dim3(256), 0, stream, texp, slots, neb, keep, idx_out);
  hipLaunchKernelGGL(k_compact,  dim3(8),    dim3(256), 0, stream, neb, slots, comp, tot);
  hipLaunchKernelGGL(k_gemm,     dim3(320),  dim3(512), 131072, stream, xb, wt, comp, tot, tprob, out);
  hipLaunchKernelGGL(k_identity, dim3(2048), dim3(256), 0, stream, x, tprob, keep, out);
}

// Round 6
// 116.408 us; speedup vs baseline: 1.0412x; 1.0072x over previous
//
#include <hip/hip_runtime.h>
#include <hip/hip_bf16.h>
#include <stdint.h>

// Problem: B=8, S=2048, D=1024, E=8, CAP=512, TOK=16384.
// Outputs (concat f32): hidden[16384*1024], logits[16384*8], expert_index[16384]

typedef __attribute__((ext_vector_type(8))) short short8;   // 8 x bf16 (4 VGPRs)
typedef __attribute__((ext_vector_type(4))) float f32x4;

#define AS1 __attribute__((address_space(1)))
#define AS3 __attribute__((address_space(3)))

static __device__ __forceinline__ uint32_t f2bf(float f) {
  __hip_bfloat16 h = __float2bfloat16(f);
  return (uint32_t)*reinterpret_cast<unsigned short*>(&h);
}

// resolve capacity-rank g within expert e -> token id, via per-(e,b) segments
static __device__ __forceinline__ int resolve_rid(const int* __restrict__ neb,
                                                  const int* __restrict__ slots,
                                                  int e, int g) {
  int acc = 0;
#pragma unroll
  for (int b = 0; b < 8; ++b) {
    int c = neb[e * 8 + b];
    if (g >= acc && g < acc + c) return slots[e * 4096 + b * 512 + (g - acc)];
    acc += c;
  }
  return slots[e * 4096];  // unreachable for valid g
}

// ---------------- Kernel 1: router (logits f32, softmax top-1) + x -> bf16 ----
__global__ __launch_bounds__(256) void k_router(
    const float* __restrict__ x, const float* __restrict__ gw,
    __hip_bfloat16* __restrict__ xb, float* __restrict__ logits,
    float* __restrict__ tprob, int* __restrict__ texp) {
  __shared__ __align__(16) float gs[8 * 1024];  // gate weights [e][d]
  const int tid = threadIdx.x;
  {
    const float4* g4 = reinterpret_cast<const float4*>(gw);
    float4* s4 = reinterpret_cast<float4*>(gs);
#pragma unroll
    for (int i = 0; i < 8; ++i) s4[tid + 256 * i] = g4[tid + 256 * i];
  }
  __syncthreads();
  const int wave = tid >> 6, lane = tid & 63;
  const int t = blockIdx.x * 4 + wave;  // one wave per token, 4096 blocks
  const float2* x2 = reinterpret_cast<const float2*>(x + (size_t)t * 1024);
  uint32_t* xbu = reinterpret_cast<uint32_t*>(xb + (size_t)t * 1024);
  const float2* g2 = reinterpret_cast<const float2*>(gs);
  float acc[8];
#pragma unroll
  for (int e = 0; e < 8; ++e) acc[e] = 0.f;
#pragma unroll
  for (int kk = 0; kk < 8; ++kk) {
    int p = lane + 64 * kk;  // float2-pair index, lane-stride-1 (conflict-free LDS)
    float2 xv = x2[p];
    xbu[p] = f2bf(xv.x) | (f2bf(xv.y) << 16);
#pragma unroll
    for (int e = 0; e < 8; ++e) {
      float2 g = g2[e * 512 + p];
      acc[e] = fmaf(xv.x, g.x, acc[e]);
      acc[e] = fmaf(xv.y, g.y, acc[e]);
    }
  }
#pragma unroll
  for (int d = 1; d < 64; d <<= 1) {
#pragma unroll
    for (int e = 0; e < 8; ++e) acc[e] += __shfl_xor(acc[e], d, 64);
  }
  if (lane == 0) {
    float m = acc[0];
    int idx = 0;
#pragma unroll
    for (int e = 1; e < 8; ++e)
      if (acc[e] > m) { m = acc[e]; idx = e; }  // strict '>' == argmax-first tiebreak
    float s = 0.f;
#pragma unroll
    for (int e = 0; e < 8; ++e) s += expf(acc[e] - m);
    tprob[t] = 1.0f / s;   // softmax prob of the max logit
    texp[t] = idx;
#pragma unroll
    for (int e = 0; e < 8; ++e) logits[(size_t)t * 8 + e] = acc[e];
  }
}

// ---------------- Kernel 2: expert_w [e][k][n] f32 -> Wt [e][n][k] bf16 -------
__global__ __launch_bounds__(256) void k_wconv(const float* __restrict__ w,
                                               __hip_bfloat16* __restrict__ wt) {
  // grid = 8 * 32 * 32 tiles of 32x32
  const int bx = blockIdx.x;
  const int e = bx >> 10;
  const int rem = bx & 1023;
  const int k0 = (rem >> 5) << 5;
  const int n0 = (rem & 31) << 5;
  __shared__ float tile[32][33];  // +1 pad: no bank conflicts on transpose
  const int tid = threadIdx.x;
  const int c = tid & 31, r0 = tid >> 5;
  const float* ws = w + (size_t)e * 1024 * 1024;
#pragma unroll
  for (int i = 0; i < 4; ++i) {
    int r = r0 + 8 * i;
    tile[r][c] = ws[(size_t)(k0 + r) * 1024 + n0 + c];
  }
  __syncthreads();
  __hip_bfloat16* wd = wt + (size_t)e * 1024 * 1024;
#pragma unroll
  for (int i = 0; i < 4; ++i) {
    int r = r0 + 8 * i;  // n within tile
    wd[(size_t)(n0 + r) * 1024 + k0 + c] = __float2bfloat16(tile[c][r]);
  }
}

// ---------------- Kernel 3: per-batch capacity scan (cumsum of onehot) --------
__global__ __launch_bounds__(256) void k_scan(
    const int* __restrict__ texp, int* __restrict__ slots, int* __restrict__ neb,
    int* __restrict__ keep, float* __restrict__ idx_out) {
  const int b = blockIdx.x;  // grid = 8
  const int tid = threadIdx.x;
  __shared__ int te_s[2048];
#pragma unroll
  for (int i = 0; i < 8; ++i) te_s[tid + 256 * i] = texp[b * 2048 + tid + 256 * i];
  __syncthreads();

  int myte[8], cnt[8];
#pragma unroll
  for (int e = 0; e < 8; ++e) cnt[e] = 0;
#pragma unroll
  for (int j = 0; j < 8; ++j) {  // thread owns 8 consecutive tokens
    int v = te_s[tid * 8 + j];
    myte[j] = v;
#pragma unroll
    for (int e = 0; e < 8; ++e) cnt[e] += (v == e);
  }
  // pack 8 counters into 4 u32 (16-bit fields; totals <= 2048 < 65536)
  unsigned u0 = (unsigned)cnt[0] | ((unsigned)cnt[1] << 16);
  unsigned u1 = (unsigned)cnt[2] | ((unsigned)cnt[3] << 16);
  unsigned u2 = (unsigned)cnt[4] | ((unsigned)cnt[5] << 16);
  unsigned u3 = (unsigned)cnt[6] | ((unsigned)cnt[7] << 16);
  const int lane = tid & 63, wave = tid >> 6;
#pragma unroll
  for (int d = 1; d < 64; d <<= 1) {  // inclusive scan within wave
    unsigned v0 = __shfl_up(u0, d, 64);
    unsigned v1 = __shfl_up(u1, d, 64);
    unsigned v2 = __shfl_up(u2, d, 64);
    unsigned v3 = __shfl_up(u3, d, 64);
    if (lane >= d) { u0 += v0; u1 += v1; u2 += v2; u3 += v3; }
  }
  __shared__ unsigned wtot[4][4];
  if (lane == 63) { wtot[wave][0] = u0; wtot[wave][1] = u1; wtot[wave][2] = u2; wtot[wave][3] = u3; }
  __syncthreads();
  unsigned a0 = 0, a1 = 0, a2 = 0, a3 = 0, s0 = 0, s1 = 0, s2 = 0, s3 = 0;
#pragma unroll
  for (int w = 0; w < 4; ++w) {
    unsigned q0 = wtot[w][0], q1 = wtot[w][1], q2 = wtot[w][2], q3 = wtot[w][3];
    if (w < wave) { a0 += q0; a1 += q1; a2 += q2; a3 += q3; }
    s0 += q0; s1 += q1; s2 += q2; s3 += q3;
  }
  u0 += a0; u1 += a1; u2 += a2; u3 += a3;  // inclusive over whole block
  int base[8];
  base[0] = (int)(u0 & 0xFFFF) - cnt[0]; base[1] = (int)(u0 >> 16) - cnt[1];
  base[2] = (int)(u1 & 0xFFFF) - cnt[2]; base[3] = (int)(u1 >> 16) - cnt[3];
  base[4] = (int)(u2 & 0xFFFF) - cnt[4]; base[5] = (int)(u2 >> 16) - cnt[5];
  base[6] = (int)(u3 & 0xFFFF) - cnt[6]; base[7] = (int)(u3 >> 16) - cnt[7];
  if (tid == 0) {
    int tt[8] = {(int)(s0 & 0xFFFF), (int)(s0 >> 16), (int)(s1 & 0xFFFF), (int)(s1 >> 16),
                 (int)(s2 & 0xFFFF), (int)(s2 >> 16), (int)(s3 & 0xFFFF), (int)(s3 >> 16)};
#pragma unroll
    for (int e = 0; e < 8; ++e) neb[e * 8 + b] = tt[e] < 512 ? tt[e] : 512;
  }
#pragma unroll
  for (int j = 0; j < 8; ++j) {
    int v = myte[j];
    int rank = 0;
#pragma unroll
    for (int e = 0; e < 8; ++e)
      if (v == e) { base[e] += 1; rank = base[e]; }  // 1-based inclusive rank
    int tok = b * 2048 + tid * 8 + j;
    int kp = rank <= 512;
    keep[tok] = kp;
    idx_out[tok] = kp ? (float)v : 0.0f;  // argmax(all-zero mask)=0 for dropped
    if (kp) slots[v * 4096 + b * 512 + rank - 1] = tok;  // deterministic, no atomics
  }
}

// ---------------- Kernel 4: gathered expert GEMM, 256x256xBK64, 8-PHASE ------
// Grid EXACTLY 256 = 8e x 8rt x 4ct (ranks 0..2047 per expert) -> one block/CU,
// ONE dispatch round, zero tail. Overflow ranks (>=2048, <=2048 worst-case) are
// handled by an appended LDS-free thin phase (32x256 chunks, register MFMA
// straight from L2-hot xb/wt). Pipeline identical to R5 (proven pass):
// 4 phases/K-tile, counted vmcnt(8), lgkm0+sched_barrier gates, setprio MFMA.
// XCD map: tile=(bid&7)*32+(bid>>3) -> XCD x <-> expert x (2MB Wt panel per L2).
__global__ __launch_bounds__(512, 2) void k_gemm(
    const __hip_bfloat16* __restrict__ xb, const __hip_bfloat16* __restrict__ wt,
    const int* __restrict__ neb, const int* __restrict__ slots,
    const float* __restrict__ tprob, float* __restrict__ out) {
  const int bid = blockIdx.x;               // 0..255
  const int tile = (bid & 7) * 32 + (bid >> 3);
  const int e = tile >> 5;
  const int local = tile & 31;
  const int rt = local >> 2;                // 256-row chunk (ranks rt*256..)
  const int ct = local & 3;                 // 256-col chunk

  extern __shared__ __align__(16) char dynls[];  // 131072 B
  __shared__ int rid_s[256];
  __shared__ float tp_s[256];

  const int tid = threadIdx.x;  // 0..511
  const int wave = tid >> 6, lane = tid & 63;
  const int wm = wave >> 2, wn = wave & 3;  // 2x4 wave grid; 128x64 out per wave
  const int frow = lane & 15, qq = lane >> 4;
  const int sw = (frow >> 1) & 3;

  int total_cap = 0;
#pragma unroll
  for (int b = 0; b < 8; ++b) total_cap += neb[e * 8 + b];
  int nvalid = total_cap - rt * 256;
  if (nvalid > 256) nvalid = 256;

  if (nvalid > 0) {
    if (tid < 256) {
      int g = rt * 256 + ((tid < nvalid) ? tid : 0);
      int rid = resolve_rid(neb, slots, e, g);
      rid_s[tid] = rid;
      tp_s[tid] = tprob[rid];
    }
    __syncthreads();

    // stage pointers: chunk cid -> row = cid>>2, slot = cid&3;
    // source k elem = (slot ^ ((row>>1)&3))*8, advanced +32 elems per event.
    const __hip_bfloat16* wte = wt + ((size_t)e << 20);
    const __hip_bfloat16 *pA0, *pA1, *pB0, *pB1;
    {
      int r0 = tid >> 2, r1 = 128 + (tid >> 2), slot = tid & 3;
      int kl0 = (slot ^ ((r0 >> 1) & 3)) * 8;
      int kl1 = (slot ^ ((r1 >> 1) & 3)) * 8;
      pA0 = xb + (size_t)rid_s[r0] * 1024 + kl0;
      pA1 = xb + (size_t)rid_s[r1] * 1024 + kl1;
      pB0 = wte + (size_t)(ct * 256 + r0) * 1024 + kl0;
      pB1 = wte + (size_t)(ct * 256 + r1) * 1024 + kl1;
    }

#define STAGE_A(bufi, kh)                                                        \
  do {                                                                           \
    char* d_ = dynls + (bufi) * 65536 + (kh) * 16384;                            \
    __builtin_amdgcn_global_load_lds((const AS1 uint32_t*)pA0,                   \
                                     (AS3 uint32_t*)(d_ + tid * 16), 16, 0, 0);  \
    __builtin_amdgcn_global_load_lds((const AS1 uint32_t*)pA1,                   \
                                     (AS3 uint32_t*)(d_ + 8192 + tid * 16), 16, 0, 0); \
    pA0 += 32; pA1 += 32;                                                        \
  } while (0)
#define STAGE_B(bufi, kh)                                                        \
  do {                                                                           \
    char* d_ = dynls + (bufi) * 65536 + 32768 + (kh) * 16384;                    \
    __builtin_amdgcn_global_load_lds((const AS1 uint32_t*)pB0,                   \
                                     (AS3 uint32_t*)(d_ + tid * 16), 16, 0, 0);  \
    __builtin_amdgcn_global_load_lds((const AS1 uint32_t*)pB1,                   \
                                     (AS3 uint32_t*)(d_ + 8192 + tid * 16), 16, 0, 0); \
    pB0 += 32; pB1 += 32;                                                        \
  } while (0)

    f32x4 acc[8][4];
#pragma unroll
    for (int i = 0; i < 8; ++i)
#pragma unroll
      for (int j = 0; j < 4; ++j) acc[i][j] = 0.f;

    const int aoffb = (wm * 128 + frow) * 64 + (qq ^ sw) * 16;  // bytes in A kh region
    const int boffb = (wn * 64 + frow) * 64 + (qq ^ sw) * 16;   // bytes in B kh region

    // prologue: K0.kh0, K0.kh1, K1.kh0
    STAGE_A(0, 0); STAGE_B(0, 0);
    STAGE_A(0, 1); STAGE_B(0, 1);
    STAGE_A(1, 0); STAGE_B(1, 0);
    asm volatile("s_waitcnt vmcnt(8)" ::: "memory");  // K0.kh0 (A+B) landed
    __builtin_amdgcn_s_barrier();
    __builtin_amdgcn_sched_barrier(0);

#define RA(mi, ks) (*reinterpret_cast<const short8*>(Ab + (ks) * 16384 + aoffb + (mi) * 1024))
#define RB(ni, ks) (*reinterpret_cast<const short8*>(Bb + (ks) * 16384 + boffb + (ni) * 1024))
#define MM(A_, B_, M_, N_) acc[M_][N_] = __builtin_amdgcn_mfma_f32_16x16x32_bf16(A_, B_, acc[M_][N_], 0, 0, 0)
#define MFMA_Q(M0_)                                                              \
  do {                                                                           \
    __builtin_amdgcn_s_setprio(1);                                               \
    MM(a0, b0, M0_ + 0, 0); MM(a0, b1, M0_ + 0, 1); MM(a0, b2, M0_ + 0, 2); MM(a0, b3, M0_ + 0, 3); \
    MM(a1, b0, M0_ + 1, 0); MM(a1, b1, M0_ + 1, 1); MM(a1, b2, M0_ + 1, 2); MM(a1, b3, M0_ + 1, 3); \
    MM(a2, b0, M0_ + 2, 0); MM(a2, b1, M0_ + 2, 1); MM(a2, b2, M0_ + 2, 2); MM(a2, b3, M0_ + 2, 3); \
    MM(a3, b0, M0_ + 3, 0); MM(a3, b1, M0_ + 3, 1); MM(a3, b2, M0_ + 3, 2); MM(a3, b3, M0_ + 3, 3); \
    __builtin_amdgcn_s_setprio(0);                                               \
  } while (0)
#define GATE()                                             \
  do {                                                     \
    __builtin_amdgcn_s_barrier();                          \
    asm volatile("s_waitcnt lgkmcnt(0)" ::: "memory");     \
    __builtin_amdgcn_sched_barrier(0);                     \
  } while (0)

    for (int u = 0; u < 16; ++u) {
      const char* Ab = dynls + (u & 1) * 65536;
      const char* Bb = Ab + 32768;
      short8 a0, a1, a2, a3, b0, b1, b2, b3;

      // ---- phase 0: ks0, mi 0-3 (+b ks0); stage A(u+1).kh1
      a0 = RA(0, 0); a1 = RA(1, 0); a2 = RA(2, 0); a3 = RA(3, 0);
      b0 = RB(0, 0); b1 = RB(1, 0); b2 = RB(2, 0); b3 = RB(3, 0);
      if (u < 15) STAGE_A((u + 1) & 1, 1);
      GATE();
      MFMA_Q(0);
      __builtin_amdgcn_s_barrier();

      // ---- phase 1: ks0, mi 4-7; stage B(u+1).kh1; vmcnt
      a0 = RA(4, 0); a1 = RA(5, 0); a2 = RA(6, 0); a3 = RA(7, 0);
      if (u < 15) STAGE_B((u + 1) & 1, 1);
      GATE();
      MFMA_Q(4);
      if (u < 15) { asm volatile("s_waitcnt vmcnt(8)" ::: "memory"); }
      else        { asm volatile("s_waitcnt vmcnt(0)" ::: "memory"); }
      __builtin_amdgcn_s_barrier();

      // ---- phase 2: ks1, mi 0-3 (+b ks1); stage A(u+2).kh0
      a0 = RA(0, 1); a1 = RA(1, 1); a2 = RA(2, 1); a3 = RA(3, 1);
      b0 = RB(0, 1); b1 = RB(1, 1); b2 = RB(2, 1); b3 = RB(3, 1);
      if (u < 14) STAGE_A(u & 1, 0);
      GATE();
      MFMA_Q(0);
      __builtin_amdgcn_s_barrier();

      // ---- phase 3: ks1, mi 4-7; stage B(u+2).kh0; vmcnt
      a0 = RA(4, 1); a1 = RA(5, 1); a2 = RA(6, 1); a3 = RA(7, 1);
      if (u < 14) STAGE_B(u & 1, 0);
      GATE();
      MFMA_Q(4);
      if (u < 14)      { asm volatile("s_waitcnt vmcnt(8)" ::: "memory"); }
      else if (u == 14){ asm volatile("s_waitcnt vmcnt(4)" ::: "memory"); }
      __builtin_amdgcn_s_barrier();
    }
#undef GATE
#undef MFMA_Q
#undef MM
#undef RB
#undef RA
#undef STAGE_B
#undef STAGE_A

    // C/D layout: col = lane&15, row = (lane>>4)*4 + j   [m89-verified]
    const int colb = ct * 256 + wn * 64 + frow;
    const int rowb = wm * 128 + qq * 4;
#pragma unroll
    for (int mi = 0; mi < 8; ++mi) {
#pragma unroll
      for (int j = 0; j < 4; ++j) {
        int r = rowb + mi * 16 + j;
        if (r < nvalid) {
          size_t ro = (size_t)rid_s[r] * 1024;
          float sc = tp_s[r];
#pragma unroll
          for (int ni = 0; ni < 4; ++ni)
            out[ro + colb + ni * 16] = sc * acc[mi][ni][j];
        }
      }
    }
  }  // nvalid > 0 (main tile)

  // ---------------- thin overflow phase (ranks >= 2048), LDS-free -------------
  // T2 thin tiles of 32 rows x 256 cols, enumerated (e, mc, ct2); block strides.
  int T2 = 0;
  {
#pragma unroll
    for (int ee = 0; ee < 8; ++ee) {
      int s = 0;
#pragma unroll
      for (int b = 0; b < 8; ++b) s += neb[ee * 8 + b];
      int ov = s - 2048; if (ov < 0) ov = 0;
      T2 += ((ov + 31) >> 5) * 4;
    }
  }
  for (int i = bid; i < T2; i += 256) {
    // decode i -> (e2, mc, ct2) without runtime-indexed arrays (rule #20)
    int e2 = 0, loc = i, found = 0;
#pragma unroll
    for (int k = 0; k < 8; ++k) {
      int s = 0;
#pragma unroll
      for (int b = 0; b < 8; ++b) s += neb[k * 8 + b];
      int ov = s - 2048; if (ov < 0) ov = 0;
      int sz = ((ov + 31) >> 5) * 4;
      if (!found) {
        if (loc < sz) { e2 = k; found = 1; } else { loc -= sz; }
      }
    }
    int tot2 = 0;
#pragma unroll
    for (int b = 0; b < 8; ++b) tot2 += neb[e2 * 8 + b];
    const int mc = loc >> 2, ct2 = loc & 3;
    int nv = tot2 - 2048 - mc * 32;
    if (nv > 32) nv = 32;

    __syncthreads();  // protect rid_s readers of previous iteration / main phase
    if (tid < 32) {
      int g = 2048 + mc * 32 + ((tid < nv) ? tid : 0);
      int rid = resolve_rid(neb, slots, e2, g);
      rid_s[tid] = rid;
      tp_s[tid] = tprob[rid];
    }
    __syncthreads();

    const __hip_bfloat16* wt2 = wt + ((size_t)e2 << 20);
    const __hip_bfloat16* pa0 = xb + (size_t)rid_s[frow] * 1024 + qq * 8;
    const __hip_bfloat16* pa1 = xb + (size_t)rid_s[16 + frow] * 1024 + qq * 8;
    const __hip_bfloat16* pb0 = wt2 + (size_t)(ct2 * 256 + wave * 32 + frow) * 1024 + qq * 8;
    const __hip_bfloat16* pb1 = pb0 + 16 * 1024;
    f32x4 tc00 = 0.f, tc01 = 0.f, tc10 = 0.f, tc11 = 0.f;
#pragma unroll 4
    for (int kk = 0; kk < 32; ++kk) {
      short8 a0 = *reinterpret_cast<const short8*>(pa0);
      short8 a1 = *reinterpret_cast<const short8*>(pa1);
      short8 b0 = *reinterpret_cast<const short8*>(pb0);
      short8 b1 = *reinterpret_cast<const short8*>(pb1);
      tc00 = __builtin_amdgcn_mfma_f32_16x16x32_bf16(a0, b0, tc00, 0, 0, 0);
      tc01 = __builtin_amdgcn_mfma_f32_16x16x32_bf16(a0, b1, tc01, 0, 0, 0);
      tc10 = __builtin_amdgcn_mfma_f32_16x16x32_bf16(a1, b0, tc10, 0, 0, 0);
      tc11 = __builtin_amdgcn_mfma_f32_16x16x32_bf16(a1, b1, tc11, 0, 0, 0);
      pa0 += 32; pa1 += 32; pb0 += 32; pb1 += 32;
    }
    const int colt = ct2 * 256 + wave * 32 + frow;
#pragma unroll
    for (int mi = 0; mi < 2; ++mi) {
#pragma unroll
      for (int j = 0; j < 4; ++j) {
        int r = mi * 16 + qq * 4 + j;
        if (r < nv) {
          float sc = tp_s[r];
          size_t ro = (size_t)rid_s[r] * 1024 + colt;
          out[ro]      = sc * (mi == 0 ? tc00[j] : tc10[j]);
          out[ro + 16] = sc * (mi == 0 ? tc01[j] : tc11[j]);
        }
      }
    }
  }
}

// ---------------- Kernel 5: identity pass-through for dropped tokens ----------
__global__ __launch_bounds__(256) void k_identity(
    const float* __restrict__ x, const float* __restrict__ tprob,
    const int* __restrict__ keep, float* __restrict__ out) {
  const int t0 = blockIdx.x * 8;  // grid = 2048
  const int tid = threadIdx.x;
#pragma unroll
  for (int j = 0; j < 8; ++j) {
    int t = t0 + j;
    if (!keep[t]) {
      float s = tprob[t];
      const float4* xi = reinterpret_cast<const float4*>(x + (size_t)t * 1024);
      float4* o = reinterpret_cast<float4*>(out + (size_t)t * 1024);
      float4 v = xi[tid];
      o[tid] = make_float4(s * v.x, s * v.y, s * v.z, s * v.w);
    }
  }
}

extern "C" void kernel_launch(void* const* d_in, const int* in_sizes, int n_in,
                              void* d_out, int out_size, void* d_ws, size_t ws_size,
                              hipStream_t stream) {
  const float* x = (const float*)d_in[0];    // [8,2048,1024]
  const float* gw = (const float*)d_in[1];   // [8,1024]
  const float* w = (const float*)d_in[2];    // [8,1024,1024]
  float* out = (float*)d_out;
  float* logits = out + (size_t)16384 * 1024;
  float* idx_out = logits + (size_t)16384 * 8;

  // workspace layout (~50.8 MB total)
  char* ws = (char*)d_ws;
  __hip_bfloat16* xb = (__hip_bfloat16*)(ws);              // 33554432 B
  __hip_bfloat16* wt = (__hip_bfloat16*)(ws + 33554432);   // 16777216 B
  float* tprob = (float*)(ws + 50331648);                  // 65536 B
  int* texp   = (int*)(ws + 50397184);                     // 65536 B
  int* keep   = (int*)(ws + 50462720);                     // 65536 B
  int* slots  = (int*)(ws + 50528256);                     // 131072 B
  int* neb    = (int*)(ws + 50659328);                     // 256 B

  hipLaunchKernelGGL(k_router,   dim3(4096), dim3(256), 0, stream, x, gw, xb, logits, tprob, texp);
  hipLaunchKernelGGL(k_wconv,    dim3(8192), dim3(256), 0, stream, w, wt);
  hipLaunchKernelGGL(k_scan,     dim3(8),    dim3(256), 0, stream, texp, slots, neb, keep, idx_out);
  hipLaunchKernelGGL(k_gemm,     dim3(256),  dim3(512), 131072, stream, xb, wt, neb, slots, tprob, out);
  hipLaunchKernelGGL(k_identity, dim3(2048), dim3(256), 0, stream, x, tprob, keep, out);
}

// Round 7
// 102.143 us; speedup vs baseline: 1.1866x; 1.1397x over previous
//
#include <hip/hip_runtime.h>
#include <hip/hip_bf16.h>
#include <stdint.h>

// Problem: B=8, S=2048, D=1024, E=8, CAP=512, TOK=16384.
// Outputs (concat f32): hidden[16384*1024], logits[16384*8], expert_index[16384]

typedef __attribute__((ext_vector_type(8))) short short8;   // 8 x bf16 (4 VGPRs)
typedef __attribute__((ext_vector_type(4))) float f32x4;

#define AS1 __attribute__((address_space(1)))
#define AS3 __attribute__((address_space(3)))

static __device__ __forceinline__ uint32_t f2bf(float f) {
  __hip_bfloat16 h = __float2bfloat16(f);
  return (uint32_t)*reinterpret_cast<unsigned short*>(&h);
}

// resolve capacity-rank g within expert e -> token id, via per-(e,b) segments
static __device__ __forceinline__ int resolve_rid(const int* __restrict__ neb,
                                                  const int* __restrict__ slots,
                                                  int e, int g) {
  int acc = 0;
#pragma unroll
  for (int b = 0; b < 8; ++b) {
    int c = neb[e * 8 + b];
    if (g >= acc && g < acc + c) return slots[e * 4096 + b * 512 + (g - acc)];
    acc += c;
  }
  return slots[e * 4096];  // unreachable for valid g
}

// ---------------- Kernel 1: router (logits f32, softmax top-1) + x -> bf16 ----
__global__ __launch_bounds__(256) void k_router(
    const float* __restrict__ x, const float* __restrict__ gw,
    __hip_bfloat16* __restrict__ xb, float* __restrict__ logits,
    float* __restrict__ tprob, int* __restrict__ texp) {
  __shared__ __align__(16) float gs[8 * 1024];  // gate weights [e][d]
  const int tid = threadIdx.x;
  {
    const float4* g4 = reinterpret_cast<const float4*>(gw);
    float4* s4 = reinterpret_cast<float4*>(gs);
#pragma unroll
    for (int i = 0; i < 8; ++i) s4[tid + 256 * i] = g4[tid + 256 * i];
  }
  __syncthreads();
  const int wave = tid >> 6, lane = tid & 63;
  const int t = blockIdx.x * 4 + wave;  // one wave per token, 4096 blocks
  const float2* x2 = reinterpret_cast<const float2*>(x + (size_t)t * 1024);
  uint32_t* xbu = reinterpret_cast<uint32_t*>(xb + (size_t)t * 1024);
  const float2* g2 = reinterpret_cast<const float2*>(gs);
  float acc[8];
#pragma unroll
  for (int e = 0; e < 8; ++e) acc[e] = 0.f;
#pragma unroll
  for (int kk = 0; kk < 8; ++kk) {
    int p = lane + 64 * kk;  // float2-pair index, lane-stride-1 (conflict-free LDS)
    float2 xv = x2[p];
    xbu[p] = f2bf(xv.x) | (f2bf(xv.y) << 16);
#pragma unroll
    for (int e = 0; e < 8; ++e) {
      float2 g = g2[e * 512 + p];
      acc[e] = fmaf(xv.x, g.x, acc[e]);
      acc[e] = fmaf(xv.y, g.y, acc[e]);
    }
  }
#pragma unroll
  for (int d = 1; d < 64; d <<= 1) {
#pragma unroll
    for (int e = 0; e < 8; ++e) acc[e] += __shfl_xor(acc[e], d, 64);
  }
  if (lane == 0) {
    float m = acc[0];
    int idx = 0;
#pragma unroll
    for (int e = 1; e < 8; ++e)
      if (acc[e] > m) { m = acc[e]; idx = e; }  // strict '>' == argmax-first tiebreak
    float s = 0.f;
#pragma unroll
    for (int e = 0; e < 8; ++e) s += expf(acc[e] - m);
    tprob[t] = 1.0f / s;   // softmax prob of the max logit
    texp[t] = idx;
#pragma unroll
    for (int e = 0; e < 8; ++e) logits[(size_t)t * 8 + e] = acc[e];
  }
}

// ---------------- Kernel 2: expert_w [e][k][n] f32 -> Wt [e][n][k] bf16 -------
__global__ __launch_bounds__(256) void k_wconv(const float* __restrict__ w,
                                               __hip_bfloat16* __restrict__ wt) {
  // grid = 8 * 32 * 32 tiles of 32x32
  const int bx = blockIdx.x;
  const int e = bx >> 10;
  const int rem = bx & 1023;
  const int k0 = (rem >> 5) << 5;
  const int n0 = (rem & 31) << 5;
  __shared__ float tile[32][33];  // +1 pad: no bank conflicts on transpose
  const int tid = threadIdx.x;
  const int c = tid & 31, r0 = tid >> 5;
  const float* ws = w + (size_t)e * 1024 * 1024;
#pragma unroll
  for (int i = 0; i < 4; ++i) {
    int r = r0 + 8 * i;
    tile[r][c] = ws[(size_t)(k0 + r) * 1024 + n0 + c];
  }
  __syncthreads();
  __hip_bfloat16* wd = wt + (size_t)e * 1024 * 1024;
#pragma unroll
  for (int i = 0; i < 4; ++i) {
    int r = r0 + 8 * i;  // n within tile
    wd[(size_t)(n0 + r) * 1024 + k0 + c] = __float2bfloat16(tile[c][r]);
  }
}

// ---------------- Kernel 3: per-batch capacity scan (cumsum of onehot) --------
__global__ __launch_bounds__(256) void k_scan(
    const int* __restrict__ texp, int* __restrict__ slots, int* __restrict__ neb,
    int* __restrict__ keep, float* __restrict__ idx_out) {
  const int b = blockIdx.x;  // grid = 8
  const int tid = threadIdx.x;
  __shared__ int te_s[2048];
#pragma unroll
  for (int i = 0; i < 8; ++i) te_s[tid + 256 * i] = texp[b * 2048 + tid + 256 * i];
  __syncthreads();

  int myte[8], cnt[8];
#pragma unroll
  for (int e = 0; e < 8; ++e) cnt[e] = 0;
#pragma unroll
  for (int j = 0; j < 8; ++j) {  // thread owns 8 consecutive tokens
    int v = te_s[tid * 8 + j];
    myte[j] = v;
#pragma unroll
    for (int e = 0; e < 8; ++e) cnt[e] += (v == e);
  }
  // pack 8 counters into 4 u32 (16-bit fields; totals <= 2048 < 65536)
  unsigned u0 = (unsigned)cnt[0] | ((unsigned)cnt[1] << 16);
  unsigned u1 = (unsigned)cnt[2] | ((unsigned)cnt[3] << 16);
  unsigned u2 = (unsigned)cnt[4] | ((unsigned)cnt[5] << 16);
  unsigned u3 = (unsigned)cnt[6] | ((unsigned)cnt[7] << 16);
  const int lane = tid & 63, wave = tid >> 6;
#pragma unroll
  for (int d = 1; d < 64; d <<= 1) {  // inclusive scan within wave
    unsigned v0 = __shfl_up(u0, d, 64);
    unsigned v1 = __shfl_up(u1, d, 64);
    unsigned v2 = __shfl_up(u2, d, 64);
    unsigned v3 = __shfl_up(u3, d, 64);
    if (lane >= d) { u0 += v0; u1 += v1; u2 += v2; u3 += v3; }
  }
  __shared__ unsigned wtot[4][4];
  if (lane == 63) { wtot[wave][0] = u0; wtot[wave][1] = u1; wtot[wave][2] = u2; wtot[wave][3] = u3; }
  __syncthreads();
  unsigned a0 = 0, a1 = 0, a2 = 0, a3 = 0, s0 = 0, s1 = 0, s2 = 0, s3 = 0;
#pragma unroll
  for (int w = 0; w < 4; ++w) {
    unsigned q0 = wtot[w][0], q1 = wtot[w][1], q2 = wtot[w][2], q3 = wtot[w][3];
    if (w < wave) { a0 += q0; a1 += q1; a2 += q2; a3 += q3; }
    s0 += q0; s1 += q1; s2 += q2; s3 += q3;
  }
  u0 += a0; u1 += a1; u2 += a2; u3 += a3;  // inclusive over whole block
  int base[8];
  base[0] = (int)(u0 & 0xFFFF) - cnt[0]; base[1] = (int)(u0 >> 16) - cnt[1];
  base[2] = (int)(u1 & 0xFFFF) - cnt[2]; base[3] = (int)(u1 >> 16) - cnt[3];
  base[4] = (int)(u2 & 0xFFFF) - cnt[4]; base[5] = (int)(u2 >> 16) - cnt[5];
  base[6] = (int)(u3 & 0xFFFF) - cnt[6]; base[7] = (int)(u3 >> 16) - cnt[7];
  if (tid == 0) {
    int tt[8] = {(int)(s0 & 0xFFFF), (int)(s0 >> 16), (int)(s1 & 0xFFFF), (int)(s1 >> 16),
                 (int)(s2 & 0xFFFF), (int)(s2 >> 16), (int)(s3 & 0xFFFF), (int)(s3 >> 16)};
#pragma unroll
    for (int e = 0; e < 8; ++e) neb[e * 8 + b] = tt[e] < 512 ? tt[e] : 512;
  }
#pragma unroll
  for (int j = 0; j < 8; ++j) {
    int v = myte[j];
    int rank = 0;
#pragma unroll
    for (int e = 0; e < 8; ++e)
      if (v == e) { base[e] += 1; rank = base[e]; }  // 1-based inclusive rank
    int tok = b * 2048 + tid * 8 + j;
    int kp = rank <= 512;
    keep[tok] = kp;
    idx_out[tok] = kp ? (float)v : 0.0f;  // argmax(all-zero mask)=0 for dropped
    if (kp) slots[v * 4096 + b * 512 + rank - 1] = tok;  // deterministic, no atomics
  }
}

// ---------------- Kernel 4: gathered expert GEMM, 256x128xBK32, 2 blocks/CU --
// T = 8e x 8rt x 8ct = 512 tiles = EXACTLY 2 blocks/CU, one round. 4 waves
// (2Mx2N, per-wave 128x64). R3's PROVEN 3-buffer depth-2 counted-vmcnt
// skeleton (best round so far): per u {vmcnt(6); barrier; STAGE(u+2);
// COMPUTE: 12 ds_read_b128 -> lgkm0+sched_barrier -> setprio 32 MFMA}.
// 1 barrier per K-step (32 total). Two co-resident blocks per CU provide the
// TLP that hides staging latency / barrier drains / prologue / epilogue (m114).
// XCD map: expert = XCD, rt-major inside -> concurrent blocks share a 0.5MB
// A-chunk + 2MB B panel (< 4MB L2/XCD; fixes R6's 6MB thrash).
// Swizzle (rule 21, R3-verified 0 conflicts): 16B chunk slot' = slot ^
// ((row>>1)&3) on pre-swizzled global source; read side slot = qq ^ ((frow>>1)&3).
__global__ __launch_bounds__(256, 2) void k_gemm(
    const __hip_bfloat16* __restrict__ xb, const __hip_bfloat16* __restrict__ wt,
    const int* __restrict__ neb, const int* __restrict__ slots,
    const float* __restrict__ tprob, float* __restrict__ out) {
  const int bid = blockIdx.x;               // 0..511
  const int tile = (bid & 7) * 64 + (bid >> 3);  // XCD x <-> expert x, rt-major
  const int e = tile >> 6;
  const int local = tile & 63;
  const int rt = local >> 3;                // 256-row chunk (ranks rt*256..)
  const int ct = local & 7;                 // 128-col chunk

  extern __shared__ __align__(16) char dynls[];  // 3 bufs x (A 16384 + B 8192) = 73728
  __shared__ int rid_s[256];
  __shared__ float tp_s[256];

  const int tid = threadIdx.x;  // 0..255
  const int wave = tid >> 6, lane = tid & 63;
  const int wm = wave >> 1, wn = wave & 1;  // 2x2 wave grid; 128x64 out per wave
  const int frow = lane & 15, qq = lane >> 4;

  int total_cap = 0;
#pragma unroll
  for (int b = 0; b < 8; ++b) total_cap += neb[e * 8 + b];
  int nvalid = total_cap - rt * 256;
  if (nvalid > 256) nvalid = 256;

  if (nvalid > 0) {
    {
      int g = rt * 256 + ((tid < nvalid) ? tid : 0);
      int rid = resolve_rid(neb, slots, e, g);
      rid_s[tid] = rid;
      tp_s[tid] = tprob[rid];
    }
    __syncthreads();

    // stage pointers: A = 1024 chunks (4/thread), B = 512 chunks (2/thread);
    // chunk cid -> row = cid>>2, slot = cid&3; src k = (slot ^ ((row>>1)&3))*8
    const __hip_bfloat16* wte = wt + ((size_t)e << 20);
    const __hip_bfloat16* pa[4];
    const __hip_bfloat16* pb[2];
#pragma unroll
    for (int p = 0; p < 4; ++p) {
      int cid = p * 256 + tid;
      int row = cid >> 2, slot = cid & 3;
      int kl = (slot ^ ((row >> 1) & 3)) * 8;
      pa[p] = xb + (size_t)rid_s[row] * 1024 + kl;
    }
#pragma unroll
    for (int p = 0; p < 2; ++p) {
      int cid = p * 256 + tid;
      int row = cid >> 2, slot = cid & 3;
      int kl = (slot ^ ((row >> 1) & 3)) * 8;
      pb[p] = wte + (size_t)(ct * 128 + row) * 1024 + kl;
    }

#define STAGE(kti, bufi)                                                           \
  do {                                                                             \
    char* d_ = dynls + (bufi) * 24576;                                             \
    _Pragma("unroll") for (int p = 0; p < 4; ++p)                                  \
      __builtin_amdgcn_global_load_lds((const AS1 uint32_t*)(pa[p] + (kti) * 32),  \
                                       (AS3 uint32_t*)(d_ + (p * 256 + tid) * 16), 16, 0, 0); \
    _Pragma("unroll") for (int p = 0; p < 2; ++p)                                  \
      __builtin_amdgcn_global_load_lds((const AS1 uint32_t*)(pb[p] + (kti) * 32),  \
                                       (AS3 uint32_t*)(d_ + 16384 + (p * 256 + tid) * 16), 16, 0, 0); \
  } while (0)

    f32x4 acc[8][4];
#pragma unroll
    for (int i = 0; i < 8; ++i)
#pragma unroll
      for (int j = 0; j < 4; ++j) acc[i][j] = 0.f;

    const int sl = qq ^ ((frow >> 1) & 3);               // read-side swizzle
    const int aoffb = (wm * 128 + frow) * 64 + sl * 16;  // bytes into A [256][32]
    const int boffb = (wn * 64 + frow) * 64 + sl * 16;   // bytes into B [128][32]

#define COMPUTE(bufi)                                                              \
  do {                                                                             \
    const char* Ab = dynls + (bufi) * 24576;                                       \
    const char* Bb = Ab + 16384;                                                   \
    short8 a[8], b[4];                                                             \
    _Pragma("unroll") for (int mi = 0; mi < 8; ++mi)                               \
        a[mi] = *reinterpret_cast<const short8*>(Ab + aoffb + mi * 1024);          \
    _Pragma("unroll") for (int ni = 0; ni < 4; ++ni)                               \
        b[ni] = *reinterpret_cast<const short8*>(Bb + boffb + ni * 1024);          \
    asm volatile("s_waitcnt lgkmcnt(0)" ::: "memory");                             \
    __builtin_amdgcn_sched_barrier(0);                                             \
    __builtin_amdgcn_s_setprio(1);                                                 \
    _Pragma("unroll") for (int mi = 0; mi < 8; ++mi)                               \
        _Pragma("unroll") for (int ni = 0; ni < 4; ++ni)                           \
            acc[mi][ni] = __builtin_amdgcn_mfma_f32_16x16x32_bf16(a[mi], b[ni], acc[mi][ni], 0, 0, 0); \
    __builtin_amdgcn_s_setprio(0);                                                 \
  } while (0)

    STAGE(0, 0);
    STAGE(1, 1);
    for (int t = 0; t < 31; ++t) {
      // buf t ready once <=6 loads (t+1's stage) remain outstanding
      asm volatile("s_waitcnt vmcnt(6)" ::: "memory");
      __builtin_amdgcn_s_barrier();
      if (t + 2 < 32) STAGE(t + 2, (t + 2) % 3);
      COMPUTE(t % 3);
    }
    asm volatile("s_waitcnt vmcnt(0)" ::: "memory");
    __builtin_amdgcn_s_barrier();
    COMPUTE(31 % 3);
#undef COMPUTE
#undef STAGE

    // C/D layout: col = lane&15, row = (lane>>4)*4 + j   [m89-verified]
    const int colb = ct * 128 + wn * 64 + frow;
    const int rowb = wm * 128 + qq * 4;
#pragma unroll
    for (int mi = 0; mi < 8; ++mi) {
#pragma unroll
      for (int j = 0; j < 4; ++j) {
        int r = rowb + mi * 16 + j;
        if (r < nvalid) {
          size_t ro = (size_t)rid_s[r] * 1024;
          float sc = tp_s[r];
#pragma unroll
          for (int ni = 0; ni < 4; ++ni)
            out[ro + colb + ni * 16] = sc * acc[mi][ni][j];
        }
      }
    }
  }  // nvalid > 0 (main tile)

  // ---------------- thin overflow phase (ranks >= 2048), LDS-free -------------
  // T2 thin tiles of 32 rows x 128 cols, enumerated (e, mc, ct2); block strides.
  int T2 = 0;
  {
#pragma unroll
    for (int ee = 0; ee < 8; ++ee) {
      int s = 0;
#pragma unroll
      for (int b = 0; b < 8; ++b) s += neb[ee * 8 + b];
      int ov = s - 2048; if (ov < 0) ov = 0;
      T2 += ((ov + 31) >> 5) * 8;
    }
  }
  for (int i = bid; i < T2; i += 512) {
    // decode i -> (e2, mc, ct2) without runtime-indexed arrays (rule #20)
    int e2 = 0, loc = i, found = 0;
#pragma unroll
    for (int k = 0; k < 8; ++k) {
      int s = 0;
#pragma unroll
      for (int b = 0; b < 8; ++b) s += neb[k * 8 + b];
      int ov = s - 2048; if (ov < 0) ov = 0;
      int sz = ((ov + 31) >> 5) * 8;
      if (!found) {
        if (loc < sz) { e2 = k; found = 1; } else { loc -= sz; }
      }
    }
    int tot2 = 0;
#pragma unroll
    for (int b = 0; b < 8; ++b) tot2 += neb[e2 * 8 + b];
    const int mc = loc >> 3, ct2 = loc & 7;
    int nv = tot2 - 2048 - mc * 32;
    if (nv > 32) nv = 32;

    __syncthreads();  // protect rid_s/tp_s readers of previous phase
    if (tid < 32) {
      int g = 2048 + mc * 32 + ((tid < nv) ? tid : 0);
      int rid = resolve_rid(neb, slots, e2, g);
      rid_s[tid] = rid;
      tp_s[tid] = tprob[rid];
    }
    __syncthreads();

    const __hip_bfloat16* wt2 = wt + ((size_t)e2 << 20);
    const __hip_bfloat16* pa0 = xb + (size_t)rid_s[frow] * 1024 + qq * 8;
    const __hip_bfloat16* pa1 = xb + (size_t)rid_s[16 + frow] * 1024 + qq * 8;
    const __hip_bfloat16* pb0 = wt2 + (size_t)(ct2 * 128 + wave * 32 + frow) * 1024 + qq * 8;
    const __hip_bfloat16* pb1 = pb0 + 16 * 1024;
    f32x4 tc00 = 0.f, tc01 = 0.f, tc10 = 0.f, tc11 = 0.f;
#pragma unroll 4
    for (int kk = 0; kk < 32; ++kk) {
      short8 a0 = *reinterpret_cast<const short8*>(pa0);
      short8 a1 = *reinterpret_cast<const short8*>(pa1);
      short8 b0 = *reinterpret_cast<const short8*>(pb0);
      short8 b1 = *reinterpret_cast<const short8*>(pb1);
      tc00 = __builtin_amdgcn_mfma_f32_16x16x32_bf16(a0, b0, tc00, 0, 0, 0);
      tc01 = __builtin_amdgcn_mfma_f32_16x16x32_bf16(a0, b1, tc01, 0, 0, 0);
      tc10 = __builtin_amdgcn_mfma_f32_16x16x32_bf16(a1, b0, tc10, 0, 0, 0);
      tc11 = __builtin_amdgcn_mfma_f32_16x16x32_bf16(a1, b1, tc11, 0, 0, 0);
      pa0 += 32; pa1 += 32; pb0 += 32; pb1 += 32;
    }
    const int colt = ct2 * 128 + wave * 32 + frow;
#pragma unroll
    for (int mi = 0; mi < 2; ++mi) {
#pragma unroll
      for (int j = 0; j < 4; ++j) {
        int r = mi * 16 + qq * 4 + j;
        if (r < nv) {
          float sc = tp_s[r];
          size_t ro = (size_t)rid_s[r] * 1024 + colt;
          out[ro]      = sc * (mi == 0 ? tc00[j] : tc10[j]);
          out[ro + 16] = sc * (mi == 0 ? tc01[j] : tc11[j]);
        }
      }
    }
  }
}

// ---------------- Kernel 5: identity pass-through for dropped tokens ----------
__global__ __launch_bounds__(256) void k_identity(
    const float* __restrict__ x, const float* __restrict__ tprob,
    const int* __restrict__ keep, float* __restrict__ out) {
  const int t0 = blockIdx.x * 8;  // grid = 2048
  const int tid = threadIdx.x;
#pragma unroll
  for (int j = 0; j < 8; ++j) {
    int t = t0 + j;
    if (!keep[t]) {
      float s = tprob[t];
      const float4* xi = reinterpret_cast<const float4*>(x + (size_t)t * 1024);
      float4* o = reinterpret_cast<float4*>(out + (size_t)t * 1024);
      float4 v = xi[tid];
      o[tid] = make_float4(s * v.x, s * v.y, s * v.z, s * v.w);
    }
  }
}

extern "C" void kernel_launch(void* const* d_in, const int* in_sizes, int n_in,
                              void* d_out, int out_size, void* d_ws, size_t ws_size,
                              hipStream_t stream) {
  const float* x = (const float*)d_in[0];    // [8,2048,1024]
  const float* gw = (const float*)d_in[1];   // [8,1024]
  const float* w = (const float*)d_in[2];    // [8,1024,1024]
  float* out = (float*)d_out;
  float* logits = out + (size_t)16384 * 1024;
  float* idx_out = logits + (size_t)16384 * 8;

  // workspace layout (~50.7 MB total)
  char* ws = (char*)d_ws;
  __hip_bfloat16* xb = (__hip_bfloat16*)(ws);              // 33554432 B
  __hip_bfloat16* wt = (__hip_bfloat16*)(ws + 33554432);   // 16777216 B
  float* tprob = (float*)(ws + 50331648);                  // 65536 B
  int* texp   = (int*)(ws + 50397184);                     // 65536 B
  int* keep   = (int*)(ws + 50462720);                     // 65536 B
  int* slots  = (int*)(ws + 50528256);                     // 131072 B
  int* neb    = (int*)(ws + 50659328);                     // 256 B

  hipLaunchKernelGGL(k_router,   dim3(4096), dim3(256), 0, stream, x, gw, xb, logits, tprob, texp);
  hipLaunchKernelGGL(k_wconv,    dim3(8192), dim3(256), 0, stream, w, wt);
  hipLaunchKernelGGL(k_scan,     dim3(8),    dim3(256), 0, stream, texp, slots, neb, keep, idx_out);
  hipLaunchKernelGGL(k_gemm,     dim3(512),  dim3(256), 73728, stream, xb, wt, neb, slots, tprob, out);
  hipLaunchKernelGGL(k_identity, dim3(2048), dim3(256), 0, stream, x, tprob, keep, out);
}

// Round 9
// 97.594 us; speedup vs baseline: 1.2419x; 1.0466x over previous
//
#include <hip/hip_runtime.h>
#include <hip/hip_bf16.h>
#include <stdint.h>

// Problem: B=8, S=2048, D=1024, E=8, CAP=512, TOK=16384.
// Outputs (concat f32): hidden[16384*1024], logits[16384*8], expert_index[16384]

typedef __attribute__((ext_vector_type(8))) short short8;   // 8 x bf16 (4 VGPRs)
typedef __attribute__((ext_vector_type(4))) float f32x4;

#define AS1 __attribute__((address_space(1)))
#define AS3 __attribute__((address_space(3)))

static __device__ __forceinline__ uint32_t f2bf(float f) {
  __hip_bfloat16 h = __float2bfloat16(f);
  return (uint32_t)*reinterpret_cast<unsigned short*>(&h);
}

// resolve capacity-rank g within expert e -> token id, via per-(e,b) segments
static __device__ __forceinline__ int resolve_rid(const int* __restrict__ neb,
                                                  const int* __restrict__ slots,
                                                  int e, int g) {
  int acc = 0;
#pragma unroll
  for (int b = 0; b < 8; ++b) {
    int c = neb[e * 8 + b];
    if (g >= acc && g < acc + c) return slots[e * 4096 + b * 512 + (g - acc)];
    acc += c;
  }
  return slots[e * 4096];  // unreachable for valid g
}

// ------- Kernel 1: FUSED router (blocks 0..4095) + wconv (blocks 4096..12287) -
__global__ __launch_bounds__(256) void k_front(
    const float* __restrict__ x, const float* __restrict__ gw,
    const float* __restrict__ w,
    __hip_bfloat16* __restrict__ xb, __hip_bfloat16* __restrict__ wt,
    float* __restrict__ logits, float* __restrict__ tprob, int* __restrict__ texp) {
  __shared__ __align__(16) float gs[8 * 1024];  // 32 KB (router); wconv reuses prefix
  const int tid = threadIdx.x;
  const int bid = blockIdx.x;

  if (bid < 4096) {
    // ---------------- router: logits f32, softmax top-1, x -> bf16 ----------
    {
      const float4* g4 = reinterpret_cast<const float4*>(gw);
      float4* s4 = reinterpret_cast<float4*>(gs);
#pragma unroll
      for (int i = 0; i < 8; ++i) s4[tid + 256 * i] = g4[tid + 256 * i];
    }
    __syncthreads();
    const int wave = tid >> 6, lane = tid & 63;
    const int t = bid * 4 + wave;  // one wave per token
    const float2* x2 = reinterpret_cast<const float2*>(x + (size_t)t * 1024);
    uint32_t* xbu = reinterpret_cast<uint32_t*>(xb + (size_t)t * 1024);
    const float2* g2 = reinterpret_cast<const float2*>(gs);
    float acc[8];
#pragma unroll
    for (int e = 0; e < 8; ++e) acc[e] = 0.f;
#pragma unroll
    for (int kk = 0; kk < 8; ++kk) {
      int p = lane + 64 * kk;  // lane-stride-1 (conflict-free LDS)
      float2 xv = x2[p];
      xbu[p] = f2bf(xv.x) | (f2bf(xv.y) << 16);
#pragma unroll
      for (int e = 0; e < 8; ++e) {
        float2 g = g2[e * 512 + p];
        acc[e] = fmaf(xv.x, g.x, acc[e]);
        acc[e] = fmaf(xv.y, g.y, acc[e]);
      }
    }
#pragma unroll
    for (int d = 1; d < 64; d <<= 1) {
#pragma unroll
      for (int e = 0; e < 8; ++e) acc[e] += __shfl_xor(acc[e], d, 64);
    }
    if (lane == 0) {
      float m = acc[0];
      int idx = 0;
#pragma unroll
      for (int e = 1; e < 8; ++e)
        if (acc[e] > m) { m = acc[e]; idx = e; }  // strict '>' == argmax-first tiebreak
      float s = 0.f;
#pragma unroll
      for (int e = 0; e < 8; ++e) s += expf(acc[e] - m);
      tprob[t] = 1.0f / s;   // softmax prob of the max logit
      texp[t] = idx;
#pragma unroll
      for (int e = 0; e < 8; ++e) logits[(size_t)t * 8 + e] = acc[e];
    }
  } else {
    // ---------------- wconv: expert_w [e][k][n] f32 -> Wt [e][n][k] bf16 ----
    const int bx = bid - 4096;             // 8192 = 8e * 32 * 32 tiles of 32x32
    const int e = bx >> 10;
    const int rem = bx & 1023;
    const int k0 = (rem >> 5) << 5;
    const int n0 = (rem & 31) << 5;
    float (*tile)[33] = reinterpret_cast<float (*)[33]>(gs);  // 32x33 pad
    const int c = tid & 31, r0 = tid >> 5;
    const float* ws = w + (size_t)e * 1024 * 1024;
#pragma unroll
    for (int i = 0; i < 4; ++i) {
      int r = r0 + 8 * i;
      tile[r][c] = ws[(size_t)(k0 + r) * 1024 + n0 + c];
    }
    __syncthreads();
    __hip_bfloat16* wd = wt + (size_t)e * 1024 * 1024;
#pragma unroll
    for (int i = 0; i < 4; ++i) {
      int r = r0 + 8 * i;  // n within tile
      wd[(size_t)(n0 + r) * 1024 + k0 + c] = __float2bfloat16(tile[c][r]);
    }
  }
}

// ---------------- Kernel 3: per-batch capacity scan (cumsum of onehot) --------
__global__ __launch_bounds__(256) void k_scan(
    const int* __restrict__ texp, int* __restrict__ slots, int* __restrict__ neb,
    int* __restrict__ keep, float* __restrict__ idx_out) {
  const int b = blockIdx.x;  // grid = 8
  const int tid = threadIdx.x;
  __shared__ int te_s[2048];
#pragma unroll
  for (int i = 0; i < 8; ++i) te_s[tid + 256 * i] = texp[b * 2048 + tid + 256 * i];
  __syncthreads();

  int myte[8], cnt[8];
#pragma unroll
  for (int e = 0; e < 8; ++e) cnt[e] = 0;
#pragma unroll
  for (int j = 0; j < 8; ++j) {  // thread owns 8 consecutive tokens
    int v = te_s[tid * 8 + j];
    myte[j] = v;
#pragma unroll
    for (int e = 0; e < 8; ++e) cnt[e] += (v == e);
  }
  // pack 8 counters into 4 u32 (16-bit fields; totals <= 2048 < 65536)
  unsigned u0 = (unsigned)cnt[0] | ((unsigned)cnt[1] << 16);
  unsigned u1 = (unsigned)cnt[2] | ((unsigned)cnt[3] << 16);
  unsigned u2 = (unsigned)cnt[4] | ((unsigned)cnt[5] << 16);
  unsigned u3 = (unsigned)cnt[6] | ((unsigned)cnt[7] << 16);
  const int lane = tid & 63, wave = tid >> 6;
#pragma unroll
  for (int d = 1; d < 64; d <<= 1) {  // inclusive scan within wave
    unsigned v0 = __shfl_up(u0, d, 64);
    unsigned v1 = __shfl_up(u1, d, 64);
    unsigned v2 = __shfl_up(u2, d, 64);
    unsigned v3 = __shfl_up(u3, d, 64);
    if (lane >= d) { u0 += v0; u1 += v1; u2 += v2; u3 += v3; }
  }
  __shared__ unsigned wtot[4][4];
  if (lane == 63) { wtot[wave][0] = u0; wtot[wave][1] = u1; wtot[wave][2] = u2; wtot[wave][3] = u3; }
  __syncthreads();
  unsigned a0 = 0, a1 = 0, a2 = 0, a3 = 0, s0 = 0, s1 = 0, s2 = 0, s3 = 0;
#pragma unroll
  for (int w = 0; w < 4; ++w) {
    unsigned q0 = wtot[w][0], q1 = wtot[w][1], q2 = wtot[w][2], q3 = wtot[w][3];
    if (w < wave) { a0 += q0; a1 += q1; a2 += q2; a3 += q3; }
    s0 += q0; s1 += q1; s2 += q2; s3 += q3;
  }
  u0 += a0; u1 += a1; u2 += a2; u3 += a3;  // inclusive over whole block
  int base[8];
  base[0] = (int)(u0 & 0xFFFF) - cnt[0]; base[1] = (int)(u0 >> 16) - cnt[1];
  base[2] = (int)(u1 & 0xFFFF) - cnt[2]; base[3] = (int)(u1 >> 16) - cnt[3];
  base[4] = (int)(u2 & 0xFFFF) - cnt[4]; base[5] = (int)(u2 >> 16) - cnt[5];
  base[6] = (int)(u3 & 0xFFFF) - cnt[6]; base[7] = (int)(u3 >> 16) - cnt[7];
  if (tid == 0) {
    int tt[8] = {(int)(s0 & 0xFFFF), (int)(s0 >> 16), (int)(s1 & 0xFFFF), (int)(s1 >> 16),
                 (int)(s2 & 0xFFFF), (int)(s2 >> 16), (int)(s3 & 0xFFFF), (int)(s3 >> 16)};
#pragma unroll
    for (int e = 0; e < 8; ++e) neb[e * 8 + b] = tt[e] < 512 ? tt[e] : 512;
  }
#pragma unroll
  for (int j = 0; j < 8; ++j) {
    int v = myte[j];
    int rank = 0;
#pragma unroll
    for (int e = 0; e < 8; ++e)
      if (v == e) { base[e] += 1; rank = base[e]; }  // 1-based inclusive rank
    int tok = b * 2048 + tid * 8 + j;
    int kp = rank <= 512;
    keep[tok] = kp;
    idx_out[tok] = kp ? (float)v : 0.0f;  // argmax(all-zero mask)=0 for dropped
    if (kp) slots[v * 4096 + b * 512 + rank - 1] = tok;  // deterministic, no atomics
  }
}

// ---------------- Kernel 4: gathered expert GEMM, 256x128xBK32, 2 blocks/CU --
// R7 geometry (512 tiles = 2 blocks/CU, one round; 4 waves 2Mx2N), 3-buffer
// counted-vmcnt(6) pipeline. Scheduling contract (fixes R8's race):
//  - each iteration tops with asm vmcnt(6) ["memory"] -> no LDS op crosses
//    iterations;
//  - sched_barrier(0) IMMEDIATELY AFTER s_barrier -> nothing (esp. ds_reads)
//    hoists above the barrier. vmcnt is PER-WAVE: buf residency is only global
//    after ALL waves executed their vmcnt and crossed the barrier (R8 bug).
//  - inside the iteration the compiler schedules ds_read<->MFMA freely with
//    fine-grained lgkmcnt (no forced lgkmcnt(0) drain).
//  - runtime WAR: every ds_read is consumed by an in-iteration MFMA, so each
//    wave's lgkm queue drains before it reaches the next barrier; a buffer is
//    rewritten >=1 barrier after its last read.
__global__ __launch_bounds__(256, 2) void k_gemm(
    const __hip_bfloat16* __restrict__ xb, const __hip_bfloat16* __restrict__ wt,
    const int* __restrict__ neb, const int* __restrict__ slots,
    const float* __restrict__ tprob, float* __restrict__ out) {
  const int bid = blockIdx.x;               // 0..511
  const int tile = (bid & 7) * 64 + (bid >> 3);  // XCD x <-> expert x, rt-major
  const int e = tile >> 6;
  const int local = tile & 63;
  const int rt = local >> 3;                // 256-row chunk (ranks rt*256..)
  const int ct = local & 7;                 // 128-col chunk

  extern __shared__ __align__(16) char dynls[];  // 3 bufs x (A 16384 + B 8192) = 73728
  __shared__ int rid_s[256];
  __shared__ float tp_s[256];

  const int tid = threadIdx.x;  // 0..255
  const int wave = tid >> 6, lane = tid & 63;
  const int wm = wave >> 1, wn = wave & 1;  // 2x2 wave grid; 128x64 out per wave
  const int frow = lane & 15, qq = lane >> 4;

  int total_cap = 0;
#pragma unroll
  for (int b = 0; b < 8; ++b) total_cap += neb[e * 8 + b];
  int nvalid = total_cap - rt * 256;
  if (nvalid > 256) nvalid = 256;

  if (nvalid > 0) {
    {
      int g = rt * 256 + ((tid < nvalid) ? tid : 0);
      int rid = resolve_rid(neb, slots, e, g);
      rid_s[tid] = rid;
      tp_s[tid] = tprob[rid];
    }
    __syncthreads();

    // stage pointers: A = 1024 chunks (4/thread), B = 512 chunks (2/thread);
    // chunk cid -> row = cid>>2, slot = cid&3; src k = (slot ^ ((row>>1)&3))*8
    const __hip_bfloat16* wte = wt + ((size_t)e << 20);
    const __hip_bfloat16* pa[4];
    const __hip_bfloat16* pb[2];
#pragma unroll
    for (int p = 0; p < 4; ++p) {
      int cid = p * 256 + tid;
      int row = cid >> 2, slot = cid & 3;
      int kl = (slot ^ ((row >> 1) & 3)) * 8;
      pa[p] = xb + (size_t)rid_s[row] * 1024 + kl;
    }
#pragma unroll
    for (int p = 0; p < 2; ++p) {
      int cid = p * 256 + tid;
      int row = cid >> 2, slot = cid & 3;
      int kl = (slot ^ ((row >> 1) & 3)) * 8;
      pb[p] = wte + (size_t)(ct * 128 + row) * 1024 + kl;
    }

#define STAGE(kti, bufi)                                                           \
  do {                                                                             \
    char* d_ = dynls + (bufi) * 24576;                                             \
    _Pragma("unroll") for (int p = 0; p < 4; ++p)                                  \
      __builtin_amdgcn_global_load_lds((const AS1 uint32_t*)(pa[p] + (kti) * 32),  \
                                       (AS3 uint32_t*)(d_ + (p * 256 + tid) * 16), 16, 0, 0); \
    _Pragma("unroll") for (int p = 0; p < 2; ++p)                                  \
      __builtin_amdgcn_global_load_lds((const AS1 uint32_t*)(pb[p] + (kti) * 32),  \
                                       (AS3 uint32_t*)(d_ + 16384 + (p * 256 + tid) * 16), 16, 0, 0); \
  } while (0)

    f32x4 acc[8][4];
#pragma unroll
    for (int i = 0; i < 8; ++i)
#pragma unroll
      for (int j = 0; j < 4; ++j) acc[i][j] = 0.f;

    const int sl = qq ^ ((frow >> 1) & 3);               // read-side swizzle
    const int aoffb = (wm * 128 + frow) * 64 + sl * 16;  // bytes into A [256][32]
    const int boffb = (wn * 64 + frow) * 64 + sl * 16;   // bytes into B [128][32]

#define COMPUTE(bufi)                                                              \
  do {                                                                             \
    const char* Ab = dynls + (bufi) * 24576;                                       \
    const char* Bb = Ab + 16384;                                                   \
    short8 a[8], b[4];                                                             \
    _Pragma("unroll") for (int mi = 0; mi < 8; ++mi)                               \
        a[mi] = *reinterpret_cast<const short8*>(Ab + aoffb + mi * 1024);          \
    _Pragma("unroll") for (int ni = 0; ni < 4; ++ni)                               \
        b[ni] = *reinterpret_cast<const short8*>(Bb + boffb + ni * 1024);          \
    __builtin_amdgcn_s_setprio(1);                                                 \
    _Pragma("unroll") for (int mi = 0; mi < 8; ++mi)                               \
        _Pragma("unroll") for (int ni = 0; ni < 4; ++ni)                           \
            acc[mi][ni] = __builtin_amdgcn_mfma_f32_16x16x32_bf16(a[mi], b[ni], acc[mi][ni], 0, 0, 0); \
    __builtin_amdgcn_s_setprio(0);                                                 \
  } while (0)

    STAGE(0, 0);
    STAGE(1, 1);
    for (int t = 0; t < 31; ++t) {
      // buf t ready once <=6 loads (t+1's stage) remain outstanding — per-wave;
      // the barrier + sched_barrier make it global and compile-time pinned.
      asm volatile("s_waitcnt vmcnt(6)" ::: "memory");
      __builtin_amdgcn_s_barrier();
      __builtin_amdgcn_sched_barrier(0);
      if (t + 2 < 32) STAGE(t + 2, (t + 2) % 3);
      COMPUTE(t % 3);
    }
    asm volatile("s_waitcnt vmcnt(0)" ::: "memory");
    __builtin_amdgcn_s_barrier();
    __builtin_amdgcn_sched_barrier(0);
    COMPUTE(31 % 3);
#undef COMPUTE
#undef STAGE

    // C/D layout: col = lane&15, row = (lane>>4)*4 + j   [m89-verified]
    const int colb = ct * 128 + wn * 64 + frow;
    const int rowb = wm * 128 + qq * 4;
#pragma unroll
    for (int mi = 0; mi < 8; ++mi) {
#pragma unroll
      for (int j = 0; j < 4; ++j) {
        int r = rowb + mi * 16 + j;
        if (r < nvalid) {
          size_t ro = (size_t)rid_s[r] * 1024;
          float sc = tp_s[r];
#pragma unroll
          for (int ni = 0; ni < 4; ++ni)
            out[ro + colb + ni * 16] = sc * acc[mi][ni][j];
        }
      }
    }
  }  // nvalid > 0 (main tile)

  // ---------------- thin overflow phase (ranks >= 2048), LDS-free -------------
  int T2 = 0;
  {
#pragma unroll
    for (int ee = 0; ee < 8; ++ee) {
      int s = 0;
#pragma unroll
      for (int b = 0; b < 8; ++b) s += neb[ee * 8 + b];
      int ov = s - 2048; if (ov < 0) ov = 0;
      T2 += ((ov + 31) >> 5) * 8;
    }
  }
  for (int i = bid; i < T2; i += 512) {
    // decode i -> (e2, mc, ct2) without runtime-indexed arrays (rule #20)
    int e2 = 0, loc = i, found = 0;
#pragma unroll
    for (int k = 0; k < 8; ++k) {
      int s = 0;
#pragma unroll
      for (int b = 0; b < 8; ++b) s += neb[k * 8 + b];
      int ov = s - 2048; if (ov < 0) ov = 0;
      int sz = ((ov + 31) >> 5) * 8;
      if (!found) {
        if (loc < sz) { e2 = k; found = 1; } else { loc -= sz; }
      }
    }
    int tot2 = 0;
#pragma unroll
    for (int b = 0; b < 8; ++b) tot2 += neb[e2 * 8 + b];
    const int mc = loc >> 3, ct2 = loc & 7;
    int nv = tot2 - 2048 - mc * 32;
    if (nv > 32) nv = 32;

    __syncthreads();  // protect rid_s/tp_s readers of previous phase
    if (tid < 32) {
      int g = 2048 + mc * 32 + ((tid < nv) ? tid : 0);
      int rid = resolve_rid(neb, slots, e2, g);
      rid_s[tid] = rid;
      tp_s[tid] = tprob[rid];
    }
    __syncthreads();

    const __hip_bfloat16* wt2 = wt + ((size_t)e2 << 20);
    const __hip_bfloat16* pa0 = xb + (size_t)rid_s[frow] * 1024 + qq * 8;
    const __hip_bfloat16* pa1 = xb + (size_t)rid_s[16 + frow] * 1024 + qq * 8;
    const __hip_bfloat16* pb0 = wt2 + (size_t)(ct2 * 128 + wave * 32 + frow) * 1024 + qq * 8;
    const __hip_bfloat16* pb1 = pb0 + 16 * 1024;
    f32x4 tc00 = 0.f, tc01 = 0.f, tc10 = 0.f, tc11 = 0.f;
#pragma unroll 4
    for (int kk = 0; kk < 32; ++kk) {
      short8 a0 = *reinterpret_cast<const short8*>(pa0);
      short8 a1 = *reinterpret_cast<const short8*>(pa1);
      short8 b0 = *reinterpret_cast<const short8*>(pb0);
      short8 b1 = *reinterpret_cast<const short8*>(pb1);
      tc00 = __builtin_amdgcn_mfma_f32_16x16x32_bf16(a0, b0, tc00, 0, 0, 0);
      tc01 = __builtin_amdgcn_mfma_f32_16x16x32_bf16(a0, b1, tc01, 0, 0, 0);
      tc10 = __builtin_amdgcn_mfma_f32_16x16x32_bf16(a1, b0, tc10, 0, 0, 0);
      tc11 = __builtin_amdgcn_mfma_f32_16x16x32_bf16(a1, b1, tc11, 0, 0, 0);
      pa0 += 32; pa1 += 32; pb0 += 32; pb1 += 32;
    }
    const int colt = ct2 * 128 + wave * 32 + frow;
#pragma unroll
    for (int mi = 0; mi < 2; ++mi) {
#pragma unroll
      for (int j = 0; j < 4; ++j) {
        int r = mi * 16 + qq * 4 + j;
        if (r < nv) {
          float sc = tp_s[r];
          size_t ro = (size_t)rid_s[r] * 1024 + colt;
          out[ro]      = sc * (mi == 0 ? tc00[j] : tc10[j]);
          out[ro + 16] = sc * (mi == 0 ? tc01[j] : tc11[j]);
        }
      }
    }
  }
}

// ---------------- Kernel 5: identity pass-through for dropped tokens ----------
__global__ __launch_bounds__(256) void k_identity(
    const float* __restrict__ x, const float* __restrict__ tprob,
    const int* __restrict__ keep, float* __restrict__ out) {
  const int t0 = blockIdx.x * 8;  // grid = 2048
  const int tid = threadIdx.x;
#pragma unroll
  for (int j = 0; j < 8; ++j) {
    int t = t0 + j;
    if (!keep[t]) {
      float s = tprob[t];
      const float4* xi = reinterpret_cast<const float4*>(x + (size_t)t * 1024);
      float4* o = reinterpret_cast<float4*>(out + (size_t)t * 1024);
      float4 v = xi[tid];
      o[tid] = make_float4(s * v.x, s * v.y, s * v.z, s * v.w);
    }
  }
}

extern "C" void kernel_launch(void* const* d_in, const int* in_sizes, int n_in,
                              void* d_out, int out_size, void* d_ws, size_t ws_size,
                              hipStream_t stream) {
  const float* x = (const float*)d_in[0];    // [8,2048,1024]
  const float* gw = (const float*)d_in[1];   // [8,1024]
  const float* w = (const float*)d_in[2];    // [8,1024,1024]
  float* out = (float*)d_out;
  float* logits = out + (size_t)16384 * 1024;
  float* idx_out = logits + (size_t)16384 * 8;

  // workspace layout (~50.7 MB total)
  char* ws = (char*)d_ws;
  __hip_bfloat16* xb = (__hip_bfloat16*)(ws);              // 33554432 B
  __hip_bfloat16* wt = (__hip_bfloat16*)(ws + 33554432);   // 16777216 B
  float* tprob = (float*)(ws + 50331648);                  // 65536 B
  int* texp   = (int*)(ws + 50397184);                     // 65536 B
  int* keep   = (int*)(ws + 50462720);                     // 65536 B
  int* slots  = (int*)(ws + 50528256);                     // 131072 B
  int* neb    = (int*)(ws + 50659328);                     // 256 B

  hipLaunchKernelGGL(k_front,    dim3(12288), dim3(256), 0, stream, x, gw, w, xb, wt, logits, tprob, texp);
  hipLaunchKernelGGL(k_scan,     dim3(8),     dim3(256), 0, stream, texp, slots, neb, keep, idx_out);
  hipLaunchKernelGGL(k_gemm,     dim3(512),   dim3(256), 73728, stream, xb, wt, neb, slots, tprob, out);
  hipLaunchKernelGGL(k_identity, dim3(2048),  dim3(256), 0, stream, x, tprob, keep, out);
}

// Round 10
// 92.278 us; speedup vs baseline: 1.3135x; 1.0576x over previous
//
#include <hip/hip_runtime.h>
#include <hip/hip_bf16.h>
#include <stdint.h>

// Problem: B=8, S=2048, D=1024, E=8, CAP=512, TOK=16384.
// Outputs (concat f32): hidden[16384*1024], logits[16384*8], expert_index[16384]

typedef __attribute__((ext_vector_type(8))) short short8;   // 8 x bf16 (4 VGPRs)
typedef __attribute__((ext_vector_type(4))) float f32x4;

#define AS1 __attribute__((address_space(1)))
#define AS3 __attribute__((address_space(3)))

static __device__ __forceinline__ uint32_t f2bf(float f) {
  __hip_bfloat16 h = __float2bfloat16(f);
  return (uint32_t)*reinterpret_cast<unsigned short*>(&h);
}

// resolve capacity-rank g within expert e -> token id, via per-(e,b) segments
static __device__ __forceinline__ int resolve_rid(const int* __restrict__ neb,
                                                  const int* __restrict__ slots,
                                                  int e, int g) {
  int acc = 0;
#pragma unroll
  for (int b = 0; b < 8; ++b) {
    int c = neb[e * 8 + b];
    if (g >= acc && g < acc + c) return slots[e * 4096 + b * 512 + (g - acc)];
    acc += c;
  }
  return slots[e * 4096];  // unreachable for valid g
}

// ------- Kernel 1: FUSED router (blocks 0..4095) + wconv (blocks 4096..12287) -
// wconv now writes Wt in K-PANEL layout: wt[e][kt][n][32], kt = k>>5.
// => every GEMM B-tile (ct,kt) is one CONTIGUOUS 8 KB region (coalesced
// global_load_lds staging), and wconv's own writes stay coalesced.
__global__ __launch_bounds__(256) void k_front(
    const float* __restrict__ x, const float* __restrict__ gw,
    const float* __restrict__ w,
    __hip_bfloat16* __restrict__ xb, __hip_bfloat16* __restrict__ wt,
    float* __restrict__ logits, float* __restrict__ tprob, int* __restrict__ texp) {
  __shared__ __align__(16) float gs[8 * 1024];  // 32 KB (router); wconv reuses prefix
  const int tid = threadIdx.x;
  const int bid = blockIdx.x;

  if (bid < 4096) {
    // ---------------- router: logits f32, softmax top-1, x -> bf16 ----------
    {
      const float4* g4 = reinterpret_cast<const float4*>(gw);
      float4* s4 = reinterpret_cast<float4*>(gs);
#pragma unroll
      for (int i = 0; i < 8; ++i) s4[tid + 256 * i] = g4[tid + 256 * i];
    }
    __syncthreads();
    const int wave = tid >> 6, lane = tid & 63;
    const int t = bid * 4 + wave;  // one wave per token
    const float2* x2 = reinterpret_cast<const float2*>(x + (size_t)t * 1024);
    uint32_t* xbu = reinterpret_cast<uint32_t*>(xb + (size_t)t * 1024);
    const float2* g2 = reinterpret_cast<const float2*>(gs);
    float acc[8];
#pragma unroll
    for (int e = 0; e < 8; ++e) acc[e] = 0.f;
#pragma unroll
    for (int kk = 0; kk < 8; ++kk) {
      int p = lane + 64 * kk;  // lane-stride-1 (conflict-free LDS)
      float2 xv = x2[p];
      xbu[p] = f2bf(xv.x) | (f2bf(xv.y) << 16);
#pragma unroll
      for (int e = 0; e < 8; ++e) {
        float2 g = g2[e * 512 + p];
        acc[e] = fmaf(xv.x, g.x, acc[e]);
        acc[e] = fmaf(xv.y, g.y, acc[e]);
      }
    }
#pragma unroll
    for (int d = 1; d < 64; d <<= 1) {
#pragma unroll
      for (int e = 0; e < 8; ++e) acc[e] += __shfl_xor(acc[e], d, 64);
    }
    if (lane == 0) {
      float m = acc[0];
      int idx = 0;
#pragma unroll
      for (int e = 1; e < 8; ++e)
        if (acc[e] > m) { m = acc[e]; idx = e; }  // strict '>' == argmax-first tiebreak
      float s = 0.f;
#pragma unroll
      for (int e = 0; e < 8; ++e) s += expf(acc[e] - m);
      tprob[t] = 1.0f / s;   // softmax prob of the max logit
      texp[t] = idx;
#pragma unroll
      for (int e = 0; e < 8; ++e) logits[(size_t)t * 8 + e] = acc[e];
    }
  } else {
    // -------- wconv: expert_w [e][k][n] f32 -> Wt K-panel [e][kt][n][32] ----
    const int bx = bid - 4096;             // 8192 = 8e * 32 * 32 tiles of 32x32
    const int e = bx >> 10;
    const int rem = bx & 1023;
    const int k0 = (rem >> 5) << 5;
    const int n0 = (rem & 31) << 5;
    float (*tile)[33] = reinterpret_cast<float (*)[33]>(gs);  // 32x33 pad
    const int c = tid & 31, r0 = tid >> 5;
    const float* ws = w + (size_t)e * 1024 * 1024;
#pragma unroll
    for (int i = 0; i < 4; ++i) {
      int r = r0 + 8 * i;
      tile[r][c] = ws[(size_t)(k0 + r) * 1024 + n0 + c];
    }
    __syncthreads();
    // dst element = e*1M + (k0>>5)*32768 + n*32 + kk
    __hip_bfloat16* wd = wt + (size_t)e * 1024 * 1024 + (size_t)(k0 >> 5) * 32768;
#pragma unroll
    for (int i = 0; i < 4; ++i) {
      int r = r0 + 8 * i;  // n within tile
      wd[(size_t)(n0 + r) * 32 + c] = __float2bfloat16(tile[c][r]);
    }
  }
}

// -------- Kernel 3: per-batch capacity scan + FUSED identity pass-through ----
__global__ __launch_bounds__(256) void k_scan(
    const int* __restrict__ texp, const float* __restrict__ x,
    int* __restrict__ slots, int* __restrict__ neb,
    float* __restrict__ tprob, float* __restrict__ idx_out,
    float* __restrict__ out) {
  const int b = blockIdx.x;  // grid = 8
  const int tid = threadIdx.x;
  __shared__ int te_s[2048];
  __shared__ int dlist[2048];
  __shared__ int ndrop;
  if (tid == 0) ndrop = 0;
#pragma unroll
  for (int i = 0; i < 8; ++i) te_s[tid + 256 * i] = texp[b * 2048 + tid + 256 * i];
  __syncthreads();

  int myte[8], cnt[8];
#pragma unroll
  for (int e = 0; e < 8; ++e) cnt[e] = 0;
#pragma unroll
  for (int j = 0; j < 8; ++j) {  // thread owns 8 consecutive tokens
    int v = te_s[tid * 8 + j];
    myte[j] = v;
#pragma unroll
    for (int e = 0; e < 8; ++e) cnt[e] += (v == e);
  }
  // pack 8 counters into 4 u32 (16-bit fields; totals <= 2048 < 65536)
  unsigned u0 = (unsigned)cnt[0] | ((unsigned)cnt[1] << 16);
  unsigned u1 = (unsigned)cnt[2] | ((unsigned)cnt[3] << 16);
  unsigned u2 = (unsigned)cnt[4] | ((unsigned)cnt[5] << 16);
  unsigned u3 = (unsigned)cnt[6] | ((unsigned)cnt[7] << 16);
  const int lane = tid & 63, wave = tid >> 6;
#pragma unroll
  for (int d = 1; d < 64; d <<= 1) {  // inclusive scan within wave
    unsigned v0 = __shfl_up(u0, d, 64);
    unsigned v1 = __shfl_up(u1, d, 64);
    unsigned v2 = __shfl_up(u2, d, 64);
    unsigned v3 = __shfl_up(u3, d, 64);
    if (lane >= d) { u0 += v0; u1 += v1; u2 += v2; u3 += v3; }
  }
  __shared__ unsigned wtot[4][4];
  if (lane == 63) { wtot[wave][0] = u0; wtot[wave][1] = u1; wtot[wave][2] = u2; wtot[wave][3] = u3; }
  __syncthreads();
  unsigned a0 = 0, a1 = 0, a2 = 0, a3 = 0, s0 = 0, s1 = 0, s2 = 0, s3 = 0;
#pragma unroll
  for (int w = 0; w < 4; ++w) {
    unsigned q0 = wtot[w][0], q1 = wtot[w][1], q2 = wtot[w][2], q3 = wtot[w][3];
    if (w < wave) { a0 += q0; a1 += q1; a2 += q2; a3 += q3; }
    s0 += q0; s1 += q1; s2 += q2; s3 += q3;
  }
  u0 += a0; u1 += a1; u2 += a2; u3 += a3;  // inclusive over whole block
  int base[8];
  base[0] = (int)(u0 & 0xFFFF) - cnt[0]; base[1] = (int)(u0 >> 16) - cnt[1];
  base[2] = (int)(u1 & 0xFFFF) - cnt[2]; base[3] = (int)(u1 >> 16) - cnt[3];
  base[4] = (int)(u2 & 0xFFFF) - cnt[4]; base[5] = (int)(u2 >> 16) - cnt[5];
  base[6] = (int)(u3 & 0xFFFF) - cnt[6]; base[7] = (int)(u3 >> 16) - cnt[7];
  if (tid == 0) {
    int tt[8] = {(int)(s0 & 0xFFFF), (int)(s0 >> 16), (int)(s1 & 0xFFFF), (int)(s1 >> 16),
                 (int)(s2 & 0xFFFF), (int)(s2 >> 16), (int)(s3 & 0xFFFF), (int)(s3 >> 16)};
#pragma unroll
    for (int e = 0; e < 8; ++e) neb[e * 8 + b] = tt[e] < 512 ? tt[e] : 512;
  }
#pragma unroll
  for (int j = 0; j < 8; ++j) {
    int v = myte[j];
    int rank = 0;
#pragma unroll
    for (int e = 0; e < 8; ++e)
      if (v == e) { base[e] += 1; rank = base[e]; }  // 1-based inclusive rank
    int tok = b * 2048 + tid * 8 + j;
    int kp = rank <= 512;
    idx_out[tok] = kp ? (float)v : 0.0f;  // argmax(all-zero mask)=0 for dropped
    if (kp) slots[v * 4096 + b * 512 + rank - 1] = tok;  // deterministic, no atomics
    else dlist[atomicAdd(&ndrop, 1)] = tok;              // LDS atomic, order-free
  }
  __syncthreads();
  // identity pass-through for dropped tokens: out[tok] = tprob[tok] * x[tok]
  const int nd = ndrop;
  for (int d = 0; d < nd; ++d) {
    int tok = dlist[d];
    float s = tprob[tok];
    const float4* xi = reinterpret_cast<const float4*>(x + (size_t)tok * 1024);
    float4* o = reinterpret_cast<float4*>(out + (size_t)tok * 1024);
    float4 v = xi[tid];
    o[tid] = make_float4(s * v.x, s * v.y, s * v.z, s * v.w);
  }
}

// ---------------- Kernel 4: gathered expert GEMM, 256x128xBK32, 2 blocks/CU --
// R9 skeleton (proven pass): 3-buffer counted-vmcnt(6), sched_barrier(0)
// pinned after every s_barrier (race-free contract), free compiler lgkmcnt
// inside the iteration. Changes vs R9:
//  - B staged from K-PANEL wt => each (ct,kt) B-tile is 8 KB contiguous:
//    fully coalesced global_load_lds (was 16 scattered 64B segs/instr).
//  - s_setprio removed (m190: hurts lockstep multi-wave GEMM).
__global__ __launch_bounds__(256, 2) void k_gemm(
    const __hip_bfloat16* __restrict__ xb, const __hip_bfloat16* __restrict__ wt,
    const int* __restrict__ neb, const int* __restrict__ slots,
    const float* __restrict__ tprob, float* __restrict__ out) {
  const int bid = blockIdx.x;               // 0..511
  const int tile = (bid & 7) * 64 + (bid >> 3);  // XCD x <-> expert x, rt-major
  const int e = tile >> 6;
  const int local = tile & 63;
  const int rt = local >> 3;                // 256-row chunk (ranks rt*256..)
  const int ct = local & 7;                 // 128-col chunk

  extern __shared__ __align__(16) char dynls[];  // 3 bufs x (A 16384 + B 8192) = 73728
  __shared__ int rid_s[256];
  __shared__ float tp_s[256];

  const int tid = threadIdx.x;  // 0..255
  const int wave = tid >> 6, lane = tid & 63;
  const int wm = wave >> 1, wn = wave & 1;  // 2x2 wave grid; 128x64 out per wave
  const int frow = lane & 15, qq = lane >> 4;

  int total_cap = 0;
#pragma unroll
  for (int b = 0; b < 8; ++b) total_cap += neb[e * 8 + b];
  int nvalid = total_cap - rt * 256;
  if (nvalid > 256) nvalid = 256;

  if (nvalid > 0) {
    {
      int g = rt * 256 + ((tid < nvalid) ? tid : 0);
      int rid = resolve_rid(neb, slots, e, g);
      rid_s[tid] = rid;
      tp_s[tid] = tprob[rid];
    }
    __syncthreads();

    // A: gathered rows (scatter forced by routing). B: contiguous panel tile.
    // chunk cid -> row = cid>>2, slot = cid&3; swizzled src chunk
    // kl = slot ^ ((row>>1)&3)  (involution; read side mirrors it)
    const __hip_bfloat16* wte = wt + ((size_t)e << 20);
    const __hip_bfloat16* pa[4];
    const __hip_bfloat16* pb[2];
#pragma unroll
    for (int p = 0; p < 4; ++p) {
      int cid = p * 256 + tid;
      int row = cid >> 2, slot = cid & 3;
      int kl = (slot ^ ((row >> 1) & 3)) * 8;
      pa[p] = xb + (size_t)rid_s[row] * 1024 + kl;
    }
#pragma unroll
    for (int p = 0; p < 2; ++p) {
      int cid = p * 256 + tid;
      int row = cid >> 2, slot = cid & 3;
      int kl = (slot ^ ((row >> 1) & 3)) * 8;
      pb[p] = wte + (size_t)ct * 4096 + (size_t)row * 32 + kl;  // within kt-panel
    }

#define STAGE(kti, bufi)                                                           \
  do {                                                                             \
    char* d_ = dynls + (bufi) * 24576;                                             \
    _Pragma("unroll") for (int p = 0; p < 4; ++p)                                  \
      __builtin_amdgcn_global_load_lds((const AS1 uint32_t*)(pa[p] + (kti) * 32),  \
                                       (AS3 uint32_t*)(d_ + (p * 256 + tid) * 16), 16, 0, 0); \
    _Pragma("unroll") for (int p = 0; p < 2; ++p)                                  \
      __builtin_amdgcn_global_load_lds((const AS1 uint32_t*)(pb[p] + (size_t)(kti) * 32768), \
                                       (AS3 uint32_t*)(d_ + 16384 + (p * 256 + tid) * 16), 16, 0, 0); \
  } while (0)

    f32x4 acc[8][4];
#pragma unroll
    for (int i = 0; i < 8; ++i)
#pragma unroll
      for (int j = 0; j < 4; ++j) acc[i][j] = 0.f;

    const int sl = qq ^ ((frow >> 1) & 3);               // read-side swizzle
    const int aoffb = (wm * 128 + frow) * 64 + sl * 16;  // bytes into A [256][32]
    const int boffb = (wn * 64 + frow) * 64 + sl * 16;   // bytes into B [128][32]

#define COMPUTE(bufi)                                                              \
  do {                                                                             \
    const char* Ab = dynls + (bufi) * 24576;                                       \
    const char* Bb = Ab + 16384;                                                   \
    short8 a[8], b[4];                                                             \
    _Pragma("unroll") for (int mi = 0; mi < 8; ++mi)                               \
        a[mi] = *reinterpret_cast<const short8*>(Ab + aoffb + mi * 1024);          \
    _Pragma("unroll") for (int ni = 0; ni < 4; ++ni)                               \
        b[ni] = *reinterpret_cast<const short8*>(Bb + boffb + ni * 1024);          \
    _Pragma("unroll") for (int mi = 0; mi < 8; ++mi)                               \
        _Pragma("unroll") for (int ni = 0; ni < 4; ++ni)                           \
            acc[mi][ni] = __builtin_amdgcn_mfma_f32_16x16x32_bf16(a[mi], b[ni], acc[mi][ni], 0, 0, 0); \
  } while (0)

    STAGE(0, 0);
    STAGE(1, 1);
    for (int t = 0; t < 31; ++t) {
      // buf t ready once <=6 loads (t+1's stage) remain outstanding — per-wave;
      // barrier + sched_barrier make it global and compile-time pinned.
      asm volatile("s_waitcnt vmcnt(6)" ::: "memory");
      __builtin_amdgcn_s_barrier();
      __builtin_amdgcn_sched_barrier(0);
      if (t + 2 < 32) STAGE(t + 2, (t + 2) % 3);
      COMPUTE(t % 3);
    }
    asm volatile("s_waitcnt vmcnt(0)" ::: "memory");
    __builtin_amdgcn_s_barrier();
    __builtin_amdgcn_sched_barrier(0);
    COMPUTE(31 % 3);
#undef COMPUTE
#undef STAGE

    // C/D layout: col = lane&15, row = (lane>>4)*4 + j   [m89-verified]
    const int colb = ct * 128 + wn * 64 + frow;
    const int rowb = wm * 128 + qq * 4;
#pragma unroll
    for (int mi = 0; mi < 8; ++mi) {
#pragma unroll
      for (int j = 0; j < 4; ++j) {
        int r = rowb + mi * 16 + j;
        if (r < nvalid) {
          size_t ro = (size_t)rid_s[r] * 1024;
          float sc = tp_s[r];
#pragma unroll
          for (int ni = 0; ni < 4; ++ni)
            out[ro + colb + ni * 16] = sc * acc[mi][ni][j];
        }
      }
    }
  }  // nvalid > 0 (main tile)

  // ---------------- thin overflow phase (ranks >= 2048), LDS-free -------------
  int T2 = 0;
  {
#pragma unroll
    for (int ee = 0; ee < 8; ++ee) {
      int s = 0;
#pragma unroll
      for (int b = 0; b < 8; ++b) s += neb[ee * 8 + b];
      int ov = s - 2048; if (ov < 0) ov = 0;
      T2 += ((ov + 31) >> 5) * 8;
    }
  }
  for (int i = bid; i < T2; i += 512) {
    // decode i -> (e2, mc, ct2) without runtime-indexed arrays (rule #20)
    int e2 = 0, loc = i, found = 0;
#pragma unroll
    for (int k = 0; k < 8; ++k) {
      int s = 0;
#pragma unroll
      for (int b = 0; b < 8; ++b) s += neb[k * 8 + b];
      int ov = s - 2048; if (ov < 0) ov = 0;
      int sz = ((ov + 31) >> 5) * 8;
      if (!found) {
        if (loc < sz) { e2 = k; found = 1; } else { loc -= sz; }
      }
    }
    int tot2 = 0;
#pragma unroll
    for (int b = 0; b < 8; ++b) tot2 += neb[e2 * 8 + b];
    const int mc = loc >> 3, ct2 = loc & 7;
    int nv = tot2 - 2048 - mc * 32;
    if (nv > 32) nv = 32;

    __syncthreads();  // protect rid_s/tp_s readers of previous phase
    if (tid < 32) {
      int g = 2048 + mc * 32 + ((tid < nv) ? tid : 0);
      int rid = resolve_rid(neb, slots, e2, g);
      rid_s[tid] = rid;
      tp_s[tid] = tprob[rid];
    }
    __syncthreads();

    const __hip_bfloat16* wt2 = wt + ((size_t)e2 << 20);
    const __hip_bfloat16* pa0 = xb + (size_t)rid_s[frow] * 1024 + qq * 8;
    const __hip_bfloat16* pa1 = xb + (size_t)rid_s[16 + frow] * 1024 + qq * 8;
    // K-panel B: row n = ct2*128 + wave*32 + frow, element = kt*32768 + n*32 + qq*8
    const __hip_bfloat16* pb0 = wt2 + (size_t)(ct2 * 128 + wave * 32 + frow) * 32 + qq * 8;
    const __hip_bfloat16* pb1 = pb0 + 16 * 32;
    f32x4 tc00 = 0.f, tc01 = 0.f, tc10 = 0.f, tc11 = 0.f;
#pragma unroll 4
    for (int kk = 0; kk < 32; ++kk) {
      short8 a0 = *reinterpret_cast<const short8*>(pa0);
      short8 a1 = *reinterpret_cast<const short8*>(pa1);
      short8 b0 = *reinterpret_cast<const short8*>(pb0);
      short8 b1 = *reinterpret_cast<const short8*>(pb1);
      tc00 = __builtin_amdgcn_mfma_f32_16x16x32_bf16(a0, b0, tc00, 0, 0, 0);
      tc01 = __builtin_amdgcn_mfma_f32_16x16x32_bf16(a0, b1, tc01, 0, 0, 0);
      tc10 = __builtin_amdgcn_mfma_f32_16x16x32_bf16(a1, b0, tc10, 0, 0, 0);
      tc11 = __builtin_amdgcn_mfma_f32_16x16x32_bf16(a1, b1, tc11, 0, 0, 0);
      pa0 += 32; pa1 += 32; pb0 += 32768; pb1 += 32768;
    }
    const int colt = ct2 * 128 + wave * 32 + frow;
#pragma unroll
    for (int mi = 0; mi < 2; ++mi) {
#pragma unroll
      for (int j = 0; j < 4; ++j) {
        int r = mi * 16 + qq * 4 + j;
        if (r < nv) {
          float sc = tp_s[r];
          size_t ro = (size_t)rid_s[r] * 1024 + colt;
          out[ro]      = sc * (mi == 0 ? tc00[j] : tc10[j]);
          out[ro + 16] = sc * (mi == 0 ? tc01[j] : tc11[j]);
        }
      }
    }
  }
}

extern "C" void kernel_launch(void* const* d_in, const int* in_sizes, int n_in,
                              void* d_out, int out_size, void* d_ws, size_t ws_size,
                              hipStream_t stream) {
  const float* x = (const float*)d_in[0];    // [8,2048,1024]
  const float* gw = (const float*)d_in[1];   // [8,1024]
  const float* w = (const float*)d_in[2];    // [8,1024,1024]
  float* out = (float*)d_out;
  float* logits = out + (size_t)16384 * 1024;
  float* idx_out = logits + (size_t)16384 * 8;

  // workspace layout (~50.7 MB total)
  char* ws = (char*)d_ws;
  __hip_bfloat16* xb = (__hip_bfloat16*)(ws);              // 33554432 B
  __hip_bfloat16* wt = (__hip_bfloat16*)(ws + 33554432);   // 16777216 B (K-panel)
  float* tprob = (float*)(ws + 50331648);                  // 65536 B
  int* texp   = (int*)(ws + 50397184);                     // 65536 B
  int* slots  = (int*)(ws + 50462720);                     // 131072 B
  int* neb    = (int*)(ws + 50593792);                     // 256 B

  hipLaunchKernelGGL(k_front, dim3(12288), dim3(256), 0, stream, x, gw, w, xb, wt, logits, tprob, texp);
  hipLaunchKernelGGL(k_scan,  dim3(8),     dim3(256), 0, stream, texp, x, slots, neb, tprob, idx_out, out);
  hipLaunchKernelGGL(k_gemm,  dim3(512),   dim3(256), 73728, stream, xb, wt, neb, slots, tprob, out);
}